// Round 12
// baseline (236.844 us; speedup 1.0000x reference)
//
#include <hip/hip_runtime.h>
#include <stdint.h>

typedef float f32x4 __attribute__((ext_vector_type(4)));
typedef __bf16 bf16x8 __attribute__((ext_vector_type(8)));

#define DEV __device__ __forceinline__

DEV unsigned short f2bf(float f) {
  unsigned u = __float_as_uint(f);
  u += 0x7FFFu + ((u >> 16) & 1u);   // round-to-nearest-even
  return (unsigned short)(u >> 16);
}

DEV float exp2_(float x) {
#if __has_builtin(__builtin_amdgcn_exp2f)
  return __builtin_amdgcn_exp2f(x);   // raw v_exp_f32; args in [-60,0] => normal range
#else
  return exp2f(x);
#endif
}

// pack two f32 -> one u32 of 2 bf16 (RNE), single instruction
DEV unsigned cvtpk(float lo, float hi) {
  unsigned r;
  asm("v_cvt_pk_bf16_f32 %0, %1, %2" : "=v"(r) : "v"(lo), "v"(hi));
  return r;
}

// a' = {a.lo32, b.lo32}; b' = {a.hi32, b.hi32}
DEV void pl32swap(unsigned &a, unsigned &b) {
#if __has_builtin(__builtin_amdgcn_permlane32_swap)
  auto r = __builtin_amdgcn_permlane32_swap(a, b, false, false);
  a = r[0]; b = r[1];
#else
  asm("v_permlane32_swap_b32 %0, %1" : "+v"(a), "+v"(b));
#endif
}

// rows = 16-lane groups: a' = {a.r0, b.r0, a.r2, b.r2}; b' = {a.r1, b.r1, a.r3, b.r3}
DEV void pl16swap(unsigned &a, unsigned &b) {
#if __has_builtin(__builtin_amdgcn_permlane16_swap)
  auto r = __builtin_amdgcn_permlane16_swap(a, b, false, false);
  a = r[0]; b = r[1];
#else
  asm("v_permlane16_swap_b32 %0, %1" : "+v"(a), "+v"(b));
#endif
}

// symmetric fake-quant of 8 packed bf16 in-register (deterministic: every
// consumer of the same bytes + same delta produces IDENTICAL results).
DEV uint4 qfrag4(uint4 w, float idq, float dq) {
  unsigned o[4];
  const unsigned* wi = &w.x;
  #pragma unroll
  for (int i = 0; i < 4; i++) {
    float lo = __uint_as_float(wi[i] << 16);
    float hi = __uint_as_float(wi[i] & 0xffff0000u);
    lo = fminf(fmaxf(rintf(lo * idq), -128.f), 127.f) * dq;
    hi = fminf(fmaxf(rintf(hi * idq), -128.f), 127.f) * dq;
    o[i] = cvtpk(lo, hi);
  }
  return make_uint4(o[0], o[1], o[2], o[3]);
}

DEV bf16x8 qfrag(uint4 w, float idq, float dq) {
  uint4 r = qfrag4(w, idq, dq);
  return *(bf16x8*)&r;
}

// scal: [0..3]=wmax(q,kv,sr,proj), [4]=qmax, [5]=kmax, [6]=vmax, [7]=pmin, [8]=pmax
// (every slot plainly written by a reducer before use; no init kernel)

// per-weight absmax partials: NO atomics (same-line atomic storms cost ~40us,
// R15-R17 evidence). Block (bx, t) writes wred[t*64 + bx].
__global__ __launch_bounds__(256) void k_absmax4(const float* w0, const float* w1,
                                                 const float* w2, const float* w3,
                                                 float* wred) {
  const float* srcs[4] = {w0, w1, w2, w3};
  const int ns[4] = {65536, 131072, 1048576, 65536};
  int t = blockIdx.y;
  const float* src = srcs[t];
  int n = ns[t];
  float m = 0.f;
  for (int i = blockIdx.x * 256 + threadIdx.x; i < n; i += gridDim.x * 256)
    m = fmaxf(m, fabsf(src[i]));
  #pragma unroll
  for (int d = 1; d < 64; d <<= 1) m = fmaxf(m, __shfl_xor(m, d, 64));
  __shared__ float red[4];
  if ((threadIdx.x & 63) == 0) red[threadIdx.x >> 6] = m;
  __syncthreads();
  if (threadIdx.x == 0) {
    m = fmaxf(fmaxf(red[0], red[1]), fmaxf(red[2], red[3]));
    wred[t * 64 + blockIdx.x] = m;
  }
}

// reduce wred[4][64] -> scal[0..3]; wave w handles weight w (64 partials)
__global__ __launch_bounds__(256) void k_redW(const float* __restrict__ wred, float* scal) {
  int t = threadIdx.x;
  float v = wred[t];
  #pragma unroll
  for (int d = 1; d < 64; d <<= 1) v = fmaxf(v, __shfl_xor(v, d, 64));
  if ((t & 63) == 0) scal[t >> 6] = v;
}

// fused weight quant + x->bf16 cast, one dispatch (grid.x = 4096):
//   all blocks:  sr_w (1048576 elems) -> sr_wq with im2col-matched k-order
//                x (8388608 f32, 8/thread) -> xb bf16
//   bx < 512:    kv_w (131072)        -> kv_wq   (slot 1)
//   bx < 256:    q_w + proj_w (65536) -> q_wq / proj_wq (slots 0 / 3)
__global__ __launch_bounds__(256) void k_quantw(const float* qw, const float* kvw,
                                                const float* prw, const float* srw,
                                                const float* xf,
                                                unsigned short* qo, unsigned short* kvo,
                                                unsigned short* pro, unsigned short* sro,
                                                unsigned short* xbo,
                                                const float* scal) {
  int bx = blockIdx.x;
  int tid = bx * 256 + threadIdx.x;
  {
    int oo = tid >> 12;
    int rem = tid & 4095;
    int khkw = rem >> 8;
    int i = rem & 255;
    float delta = scal[2] / 127.f + 1e-8f;
    float x = srw[oo * 4096 + i * 16 + khkw];
    sro[tid] = f2bf(fminf(fmaxf(rintf(x / delta), -128.f), 127.f) * delta);
  }
  {
    // x cast: 8 contiguous f32 -> 8 bf16 per thread
    const float4* xs = (const float4*)(xf + (size_t)tid * 8);
    float4 v0 = xs[0], v1 = xs[1];
    unsigned w0 = ((unsigned)f2bf(v0.y) << 16) | f2bf(v0.x);
    unsigned w1 = ((unsigned)f2bf(v0.w) << 16) | f2bf(v0.z);
    unsigned w2 = ((unsigned)f2bf(v1.y) << 16) | f2bf(v1.x);
    unsigned w3 = ((unsigned)f2bf(v1.w) << 16) | f2bf(v1.z);
    *(uint4*)(xbo + (size_t)tid * 8) = make_uint4(w0, w1, w2, w3);
  }
  if (bx < 512) {
    float delta = scal[1] / 127.f + 1e-8f;
    kvo[tid] = f2bf(fminf(fmaxf(rintf(kvw[tid] / delta), -128.f), 127.f) * delta);
  }
  if (bx < 256) {
    float dq = scal[0] / 127.f + 1e-8f;
    qo[tid] = f2bf(fminf(fmaxf(rintf(qw[tid] / dq), -128.f), 127.f) * dq);
    float dp = scal[3] / 127.f + 1e-8f;
    pro[tid] = f2bf(fminf(fmaxf(rintf(prw[tid] / dp), -128.f), 127.f) * dp);
  }
}

// ---- FUSED kv-GEMM + q-GEMM, one dispatch (768 blocks) ----
// Per-wave amax -> wredG[bid*4+wid] (plain stores; NO same-line atomics).
__global__ __launch_bounds__(256) void k_gemm_qkv(const unsigned short* __restrict__ xnrm,
                                                  const unsigned short* __restrict__ kvw,
                                                  const float* __restrict__ kvb,
                                                  const unsigned short* __restrict__ xb,
                                                  const unsigned short* __restrict__ qw,
                                                  const float* __restrict__ qb,
                                                  unsigned short* __restrict__ kqu,
                                                  unsigned short* __restrict__ vqtu,
                                                  unsigned short* __restrict__ qq,
                                                  float* __restrict__ wredG) {
  __shared__ unsigned short smem[18432];  // 36.9 KB union
  const int tid = threadIdx.x;
  const int wid = tid >> 6, lane = tid & 63;
  const int quad = lane >> 4, lr = lane & 15;
  const int wm = wid >> 1, wn = wid & 1;
  if (blockIdx.x < 256) {
    // ---------------- kv GEMM ----------------
    unsigned short* As = smem;            // 64*136
    unsigned short* Bs = smem + 8704;     // 64*136
    const int n0 = (blockIdx.x & 7) * 64, m0 = (blockIdx.x >> 3) * 64;
    f32x4 acc[2][2] = {};
    for (int kb = 0; kb < 256; kb += 128) {
      __syncthreads();
      #pragma unroll
      for (int i = 0; i < 4; i++) {
        int c = i * 256 + tid;
        int row = c >> 4, cu = (c & 15) * 8;
        *(uint4*)&As[row * 136 + cu] = *(const uint4*)(xnrm + (size_t)(m0 + row) * 256 + kb + cu);
        *(uint4*)&Bs[row * 136 + cu] = *(const uint4*)(kvw + (size_t)(n0 + row) * 256 + kb + cu);
      }
      __syncthreads();
      #pragma unroll
      for (int kc = 0; kc < 4; kc++) {
        bf16x8 af0 = *(const bf16x8*)&As[(wm * 32 + lr) * 136 + kc * 32 + quad * 8];
        bf16x8 af1 = *(const bf16x8*)&As[(wm * 32 + 16 + lr) * 136 + kc * 32 + quad * 8];
        bf16x8 bf0 = *(const bf16x8*)&Bs[(wn * 32 + lr) * 136 + kc * 32 + quad * 8];
        bf16x8 bf1 = *(const bf16x8*)&Bs[(wn * 32 + 16 + lr) * 136 + kc * 32 + quad * 8];
        acc[0][0] = __builtin_amdgcn_mfma_f32_16x16x32_bf16(af0, bf0, acc[0][0], 0, 0, 0);
        acc[0][1] = __builtin_amdgcn_mfma_f32_16x16x32_bf16(af0, bf1, acc[0][1], 0, 0, 0);
        acc[1][0] = __builtin_amdgcn_mfma_f32_16x16x32_bf16(af1, bf0, acc[1][0], 0, 0, 0);
        acc[1][1] = __builtin_amdgcn_mfma_f32_16x16x32_bf16(af1, bf1, acc[1][1], 0, 0, 0);
      }
    }
    float amax = 0.f;
    #pragma unroll
    for (int mi = 0; mi < 2; mi++)
      #pragma unroll
      for (int ni = 0; ni < 2; ni++) {
        int col = n0 + wn * 32 + ni * 16 + lr;
        float bv = kvb[col];
        #pragma unroll
        for (int r = 0; r < 4; r++) {
          int row = m0 + wm * 32 + mi * 16 + quad * 4 + r;
          float v = acc[mi][ni][r] + bv;
          int b = row >> 8, n2 = row & 255;
          int h = (col >> 5) & 7, j = col & 31;
          if (col < 256)
            kqu[((size_t)((b * 8 + h) * 256 + n2)) * 32 + j] = f2bf(v);
          else
            vqtu[((size_t)((b * 8 + h) * 32 + j)) * 256 + n2] = f2bf(v);
          amax = fmaxf(amax, fabsf(v));
        }
      }
    #pragma unroll
    for (int d = 1; d < 64; d <<= 1) amax = fmaxf(amax, __shfl_xor(amax, d, 64));
    if (lane == 0) wredG[(blockIdx.x << 2) | wid] = amax;
  } else {
    // ---------------- q GEMM (XCD-swizzled 128x128) ----------------
    unsigned short* As = smem;            // 128*72
    unsigned short* Bs = smem + 9216;     // 128*72
    const int id = blockIdx.x - 256;
    const int xcd = id & 7, idx = id >> 3;          // 64 blocks per XCD
    const int mt = xcd * 32 + (idx >> 1), nt = idx & 1;
    const int m0 = mt * 128, n0 = nt * 128;
    f32x4 acc[4][4] = {};
    for (int kb = 0; kb < 256; kb += 64) {
      __syncthreads();
      #pragma unroll
      for (int i = 0; i < 4; i++) {
        int c = i * 256 + tid;
        int row = c >> 3, cu = (c & 7) * 8;
        *(uint4*)&As[row * 72 + cu] = *(const uint4*)(xb + (size_t)(m0 + row) * 256 + kb + cu);
        *(uint4*)&Bs[row * 72 + cu] = *(const uint4*)(qw + (size_t)(n0 + row) * 256 + kb + cu);
      }
      __syncthreads();
      #pragma unroll
      for (int kc = 0; kc < 2; kc++) {
        bf16x8 af[4], bf[4];
        #pragma unroll
        for (int mi = 0; mi < 4; mi++)
          af[mi] = *(const bf16x8*)&As[(wm * 64 + mi * 16 + lr) * 72 + kc * 32 + quad * 8];
        #pragma unroll
        for (int ni = 0; ni < 4; ni++)
          bf[ni] = *(const bf16x8*)&Bs[(wn * 64 + ni * 16 + lr) * 72 + kc * 32 + quad * 8];
        #pragma unroll
        for (int mi = 0; mi < 4; mi++)
          #pragma unroll
          for (int ni = 0; ni < 4; ni++)
            acc[mi][ni] = __builtin_amdgcn_mfma_f32_16x16x32_bf16(af[mi], bf[ni], acc[mi][ni], 0, 0, 0);
      }
    }
    float amax = 0.f;
    #pragma unroll
    for (int mi = 0; mi < 4; mi++)
      #pragma unroll
      for (int ni = 0; ni < 4; ni++) {
        int col = n0 + wn * 64 + ni * 16 + lr;
        float bv = qb[col];
        #pragma unroll
        for (int r = 0; r < 4; r++) {
          int row = m0 + wm * 64 + mi * 16 + quad * 4 + r;
          float v = acc[mi][ni][r] + bv;
          int b = row >> 12, nn = row & 4095;
          int h = col >> 5, j = col & 31;
          qq[((size_t)(b * 8 + h) * 4096 + nn) * 32 + j] = f2bf(v);
          amax = fmaxf(amax, fabsf(v));
        }
      }
    #pragma unroll
    for (int d = 1; d < 64; d <<= 1) amax = fmaxf(amax, __shfl_xor(amax, d, 64));
    if (lane == 0) wredG[(blockIdx.x << 2) | wid] = amax;
  }
}

// reduce wredG[3072] -> scal[4]=qmax, scal[5]=kmax, scal[6]=vmax
__global__ __launch_bounds__(256) void k_redG(const float* __restrict__ wredG, float* scal) {
  int t = threadIdx.x, wid = t >> 6, lane = t & 63;
  float mk = 0.f, mv = 0.f, mq = 0.f;
  #pragma unroll
  for (int i = 0; i < 12; i++) {
    int idx = t + i * 256;
    float v = wredG[idx];
    int bid = idx >> 2;
    if (bid < 256) {
      if ((bid & 7) < 4) mk = fmaxf(mk, v);
      else               mv = fmaxf(mv, v);
    } else {
      mq = fmaxf(mq, v);
    }
  }
  #pragma unroll
  for (int d = 1; d < 64; d <<= 1) {
    mk = fmaxf(mk, __shfl_xor(mk, d, 64));
    mv = fmaxf(mv, __shfl_xor(mv, d, 64));
    mq = fmaxf(mq, __shfl_xor(mq, d, 64));
  }
  __shared__ float red[12];
  if (lane == 0) { red[wid] = mk; red[4 + wid] = mv; red[8 + wid] = mq; }
  __syncthreads();
  if (t == 0) {
    scal[5] = fmaxf(fmaxf(red[0], red[1]), fmaxf(red[2], red[3]));
    scal[6] = fmaxf(fmaxf(red[4], red[5]), fmaxf(red[6], red[7]));
    scal[4] = fmaxf(fmaxf(red[8], red[9]), fmaxf(red[10], red[11]));
  }
}

// ---- 128x128-tile GEMM (proj): f32 C out, XCD-swizzled ----
__global__ __launch_bounds__(256) void k_gemm128(const unsigned short* __restrict__ Ab,
                                                 const unsigned short* __restrict__ W,
                                                 const float* __restrict__ bias,
                                                 float* __restrict__ C) {
  __shared__ unsigned short As[128 * 72];
  __shared__ unsigned short Bs[128 * 72];
  const int id = blockIdx.x;
  const int xcd = id & 7, idx = id >> 3;
  const int mt = xcd * 32 + (idx >> 1), nt = idx & 1;
  const int m0 = mt * 128, n0 = nt * 128;
  const int tid = threadIdx.x;
  const int wid = tid >> 6, lane = tid & 63;
  const int quad = lane >> 4, lr = lane & 15;
  const int wm = wid >> 1, wn = wid & 1;
  f32x4 acc[4][4] = {};
  for (int kb = 0; kb < 256; kb += 64) {
    __syncthreads();
    #pragma unroll
    for (int i = 0; i < 4; i++) {
      int c = i * 256 + tid;
      int row = c >> 3, cu = (c & 7) * 8;
      *(uint4*)&As[row * 72 + cu] = *(const uint4*)(Ab + (size_t)(m0 + row) * 256 + kb + cu);
      *(uint4*)&Bs[row * 72 + cu] = *(const uint4*)(W + (size_t)(n0 + row) * 256 + kb + cu);
    }
    __syncthreads();
    #pragma unroll
    for (int kc = 0; kc < 2; kc++) {
      bf16x8 af[4], bf[4];
      #pragma unroll
      for (int mi = 0; mi < 4; mi++)
        af[mi] = *(const bf16x8*)&As[(wm * 64 + mi * 16 + lr) * 72 + kc * 32 + quad * 8];
      #pragma unroll
      for (int ni = 0; ni < 4; ni++)
        bf[ni] = *(const bf16x8*)&Bs[(wn * 64 + ni * 16 + lr) * 72 + kc * 32 + quad * 8];
      #pragma unroll
      for (int mi = 0; mi < 4; mi++)
        #pragma unroll
        for (int ni = 0; ni < 4; ni++)
          acc[mi][ni] = __builtin_amdgcn_mfma_f32_16x16x32_bf16(af[mi], bf[ni], acc[mi][ni], 0, 0, 0);
    }
  }
  #pragma unroll
  for (int mi = 0; mi < 4; mi++)
    #pragma unroll
    for (int ni = 0; ni < 4; ni++) {
      int col = n0 + wn * 64 + ni * 16 + lr;
      float bv = bias[col];
      #pragma unroll
      for (int r = 0; r < 4; r++) {
        int row = m0 + wm * 64 + mi * 16 + quad * 4 + r;
        C[(size_t)row * 256 + col] = acc[mi][ni][r] + bv;
      }
    }
}

// ---- conv GEMM: 2048x256xK4096, split-K=4, im2col fused (bf16 x); flat grid 512
__global__ __launch_bounds__(256) void k_conv_sk(const unsigned short* __restrict__ xb,
                                                 const unsigned short* __restrict__ W,
                                                 float* __restrict__ C) {
  __shared__ unsigned short As[64 * 136];
  __shared__ unsigned short Bs[64 * 136];
  const int id = blockIdx.x;
  const int xcd = id & 7, idx = id >> 3;
  const int a = idx >> 2, nt = idx & 3;
  const int ag = xcd * 16 + a;
  const int mt = ag & 31, z = ag >> 5;
  const int m0 = mt * 64, n0 = nt * 64;
  const int kOff = z * 1024;
  C += (size_t)z * 2048 * 256;
  const int tid = threadIdx.x;
  const int wid = tid >> 6, lane = tid & 63;
  const int quad = lane >> 4, lr = lane & 15;
  const int wm = wid >> 1, wn = wid & 1;
  f32x4 acc[2][2] = {};
  for (int kb = 0; kb < 1024; kb += 128) {
    __syncthreads();
    #pragma unroll
    for (int i = 0; i < 4; i++) {
      int c = i * 256 + tid;
      int row = c >> 4, cu = (c & 15) * 8;
      int kk = kOff + kb + cu;
      int m = m0 + row;
      int b = m >> 8, p = m & 255, ph = p >> 4, pw = p & 15;
      int q = kk >> 8, ii = kk & 255;
      int n = (ph * 4 + (q >> 2)) * 64 + pw * 4 + (q & 3);
      *(uint4*)&As[row * 136 + cu] = *(const uint4*)(xb + ((size_t)(b * 4096 + n) * 256 + ii));
      *(uint4*)&Bs[row * 136 + cu] = *(const uint4*)(W + (size_t)(n0 + row) * 4096 + kk);
    }
    __syncthreads();
    #pragma unroll
    for (int kc = 0; kc < 4; kc++) {
      bf16x8 af0 = *(const bf16x8*)&As[(wm * 32 + lr) * 136 + kc * 32 + quad * 8];
      bf16x8 af1 = *(const bf16x8*)&As[(wm * 32 + 16 + lr) * 136 + kc * 32 + quad * 8];
      bf16x8 bf0 = *(const bf16x8*)&Bs[(wn * 32 + lr) * 136 + kc * 32 + quad * 8];
      bf16x8 bf1 = *(const bf16x8*)&Bs[(wn * 32 + 16 + lr) * 136 + kc * 32 + quad * 8];
      acc[0][0] = __builtin_amdgcn_mfma_f32_16x16x32_bf16(af0, bf0, acc[0][0], 0, 0, 0);
      acc[0][1] = __builtin_amdgcn_mfma_f32_16x16x32_bf16(af0, bf1, acc[0][1], 0, 0, 0);
      acc[1][0] = __builtin_amdgcn_mfma_f32_16x16x32_bf16(af1, bf0, acc[1][0], 0, 0, 0);
      acc[1][1] = __builtin_amdgcn_mfma_f32_16x16x32_bf16(af1, bf1, acc[1][1], 0, 0, 0);
    }
  }
  #pragma unroll
  for (int mi = 0; mi < 2; mi++)
    #pragma unroll
    for (int ni = 0; ni < 2; ni++) {
      int col = n0 + wn * 32 + ni * 16 + lr;
      #pragma unroll
      for (int r = 0; r < 4; r++) {
        int row = m0 + wm * 32 + mi * 16 + quad * 4 + r;
        C[(size_t)row * 256 + col] = acc[mi][ni][r];
      }
    }
}

// LayerNorm over C=256; sums 4 split-K conv partials + sr_b first
__global__ __launch_bounds__(256) void k_ln(const float* __restrict__ convp, const float* srb,
                                            const float* g, const float* bb,
                                            unsigned short* __restrict__ xn) {
  int row = blockIdx.x, c = threadIdx.x;
  float v = srb[c];
  #pragma unroll
  for (int s = 0; s < 4; s++) v += convp[s * 524288 + row * 256 + c];
  __shared__ float red[4];
  float s = v;
  #pragma unroll
  for (int d = 1; d < 64; d <<= 1) s += __shfl_xor(s, d, 64);
  if ((c & 63) == 0) red[c >> 6] = s;
  __syncthreads();
  float mu = (red[0] + red[1] + red[2] + red[3]) * (1.f / 256.f);
  __syncthreads();
  float dv = v - mu;
  float s2 = dv * dv;
  #pragma unroll
  for (int d = 1; d < 64; d <<= 1) s2 += __shfl_xor(s2, d, 64);
  if ((c & 63) == 0) red[c >> 6] = s2;
  __syncthreads();
  float var = (red[0] + red[1] + red[2] + red[3]) * (1.f / 256.f);
  float rs = 1.f / sqrtf(var + 1e-5f);
  xn[row * 256 + c] = f2bf(dv * rs * g[c] + bb[c]);
}

// attention pass 1: swapped QK^T; K staged lane-major + fake-quant in staging;
// q quantized in-register. Per-block (wmin,wmax) -> pstat (no atomics).
// Grid 32x64 (2 row-groups/block) for TLP.
__global__ __launch_bounds__(256) void k_attn1(const unsigned short* __restrict__ qq,
                                               const unsigned short* __restrict__ kqu,
                                               float2* __restrict__ rowstats,
                                               const float* __restrict__ scal,
                                               float2* __restrict__ pstat) {
  __shared__ unsigned short KsL[8192];  // 16 KB: [t(16)][lane(64)] x 8 shorts
  __shared__ float red[8];
  const int bh = blockIdx.y;
  const int row0 = blockIdx.x * 128;
  const int tid = threadIdx.x, wid = tid >> 6, lane = tid & 63, quad = lane >> 4, lr = lane & 15;
  const float c2 = 0.17677669529663687f * 1.4426950408889634f;  // 32^-0.5 * log2(e)
  const unsigned short* kb = kqu + (size_t)bh * 8192;
  float dk = scal[5] / 127.f + 1e-8f;
  float idk = 1.f / dk;
  float dq = scal[4] / 127.f + 1e-8f;
  float idq = 1.f / dq;
  #pragma unroll
  for (int k = 0; k < 4; k++) {
    int cid = k * 256 + tid;                 // 1024 chunks of 16B
    int seg = cid >> 6, lc = cid & 63, qc = lc >> 4, lrc = lc & 15;
    uint4 kw = *(const uint4*)(kb + (seg * 16 + lrc) * 32 + qc * 8);
    *(uint4*)&KsL[cid * 8] = qfrag4(kw, idk, dk);
  }
  __syncthreads();
  float wmin = 1e30f, wmax = 0.f;
  #pragma unroll
  for (int g = 0; g < 2; g++) {
    int rowg = row0 + g * 64 + wid * 16 + lr;
    uint4 qw = *(const uint4*)(qq + ((size_t)bh * 4096 + rowg) * 32 + quad * 8);
    bf16x8 qf = qfrag(qw, idq, dq);
    f32x4 acc[16] = {};
    #pragma unroll
    for (int t = 0; t < 16; t++) {
      bf16x8 kf = *(const bf16x8*)&KsL[(t * 64 + quad * 16 + lr) * 8];
      acc[t] = __builtin_amdgcn_mfma_f32_16x16x32_bf16(kf, qf, acc[t], 0, 0, 0);
    }
    float mxr = -1e30f, mnr = 1e30f;
    #pragma unroll
    for (int t = 0; t < 16; t++)
      #pragma unroll
      for (int r = 0; r < 4; r++) {
        float s = acc[t][r];
        mxr = fmaxf(mxr, s); mnr = fminf(mnr, s);
      }
    #pragma unroll
    for (int d = 16; d < 64; d <<= 1) {
      mxr = fmaxf(mxr, __shfl_xor(mxr, d, 64));
      mnr = fminf(mnr, __shfl_xor(mnr, d, 64));
    }
    float m2 = mxr * c2;
    float l = 0.f;
    #pragma unroll
    for (int t = 0; t < 16; t++)
      #pragma unroll
      for (int r = 0; r < 4; r++)
        l += exp2_(fmaf(acc[t][r], c2, -m2));
    #pragma unroll
    for (int d = 16; d < 64; d <<= 1) l += __shfl_xor(l, d, 64);
    float inv_l = 1.f / l;
    if (lane < 16)
      rowstats[(size_t)bh * 4096 + rowg] = make_float2(m2, inv_l);
    wmax = fmaxf(wmax, inv_l);
    wmin = fminf(wmin, exp2_((mnr - mxr) * c2) * inv_l);
  }
  #pragma unroll
  for (int d = 1; d < 16; d <<= 1) {
    wmax = fmaxf(wmax, __shfl_xor(wmax, d, 64));
    wmin = fminf(wmin, __shfl_xor(wmin, d, 64));
  }
  if (lane == 0) { red[wid] = wmin; red[4 + wid] = wmax; }
  __syncthreads();
  if (tid == 0) {
    float mn = fminf(fminf(red[0], red[1]), fminf(red[2], red[3]));
    float mx = fmaxf(fmaxf(red[4], red[5]), fmaxf(red[6], red[7]));
    pstat[blockIdx.y * 32 + blockIdx.x] = make_float2(mn, mx);
  }
}

// reduce pstat[2048] -> scal[7]=pmin, scal[8]=pmax  (single block)
__global__ __launch_bounds__(256) void k_pminmax(const float2* __restrict__ pstat, float* scal) {
  int t = threadIdx.x;
  float mn = 1e30f, mx = 0.f;
  #pragma unroll
  for (int i = 0; i < 8; i++) {
    float2 v = pstat[t + i * 256];
    mn = fminf(mn, v.x); mx = fmaxf(mx, v.y);
  }
  #pragma unroll
  for (int d = 1; d < 64; d <<= 1) {
    mn = fminf(mn, __shfl_xor(mn, d, 64));
    mx = fmaxf(mx, __shfl_xor(mx, d, 64));
  }
  __shared__ float red[8];
  if ((t & 63) == 0) { red[t >> 6] = mn; red[4 + (t >> 6)] = mx; }
  __syncthreads();
  if (t == 0) {
    scal[7] = fminf(fminf(red[0], red[1]), fminf(red[2], red[3]));
    scal[8] = fmaxf(fmaxf(red[4], red[5]), fmaxf(red[6], red[7]));
  }
}

// attention pass 2: swapped-QK in-register softmax/quant; K/V staged lane-major
// with fake-quant in staging; q quantized on load. R20: grid 32x64 (2 row-groups)
// mirroring attn1's verified R16 change — more independent blocks for TLP.
__global__ __launch_bounds__(256) void k_attn2(const unsigned short* __restrict__ qq,
                                               const unsigned short* __restrict__ kqu,
                                               const unsigned short* __restrict__ vqtu,
                                               const float* __restrict__ scal,
                                               const float2* __restrict__ rowstats,
                                               unsigned short* __restrict__ attn_out) {
  __shared__ unsigned short KsL[8192];  // 16 KB: [t(16)][lane(64)] chunks
  __shared__ unsigned short VsL[8192];  // 16 KB: [ks*2+half(16)][lane(64)] chunks
  const int bh = blockIdx.y, b = bh >> 3, h = bh & 7;
  const int row0 = blockIdx.x * 128;
  const int tid = threadIdx.x, wid = tid >> 6, lane = tid & 63, quad = lane >> 4, lr = lane & 15;
  const float c2 = 0.17677669529663687f * 1.4426950408889634f;
  const unsigned short* kb = kqu + (size_t)bh * 8192;
  const unsigned short* vb = vqtu + (size_t)bh * 8192;
  float dk = scal[5] / 127.f + 1e-8f;
  float idk = 1.f / dk;
  float dv = scal[6] / 127.f + 1e-8f;
  float idv = 1.f / dv;
  float dq = scal[4] / 127.f + 1e-8f;
  float idq = 1.f / dq;
  #pragma unroll
  for (int k = 0; k < 4; k++) {
    int cid = k * 256 + tid;
    int seg = cid >> 6, lc = cid & 63, qc = lc >> 4, lrc = lc & 15;
    uint4 kw = *(const uint4*)(kb + (seg * 16 + lrc) * 32 + qc * 8);
    *(uint4*)&KsL[cid * 8] = qfrag4(kw, idk, dk);
    uint4 vw = *(const uint4*)(vb + ((seg & 1) * 16 + lrc) * 256 + (seg >> 1) * 32 + qc * 8);
    *(uint4*)&VsL[cid * 8] = qfrag4(vw, idv, dv);
  }
  float pmin = scal[7], pmax = scal[8];
  float delta = (pmax - pmin) / 255.f + 1e-8f;
  float zp = rintf(-pmin / delta);
  float qlo = -zp, qhi = 255.f - zp;
  __syncthreads();
  #pragma unroll
  for (int g = 0; g < 2; g++) {
    int rowg = row0 + g * 64 + wid * 16 + lr;
    uint4 qw = *(const uint4*)(qq + ((size_t)bh * 4096 + rowg) * 32 + quad * 8);
    bf16x8 qf = qfrag(qw, idq, dq);
    float2 st = rowstats[(size_t)bh * 4096 + rowg];
    f32x4 acc[16] = {};
    #pragma unroll
    for (int t = 0; t < 16; t++) {
      bf16x8 kf = *(const bf16x8*)&KsL[(t * 64 + quad * 16 + lr) * 8];
      acc[t] = __builtin_amdgcn_mfma_f32_16x16x32_bf16(kf, qf, acc[t], 0, 0, 0);
    }
    float ofs = __log2f(st.y / delta) - st.x;
    f32x4 o0 = {}, o1 = {};
    #pragma unroll
    for (int ks = 0; ks < 8; ks++) {
      float pv[8];
      #pragma unroll
      for (int half = 0; half < 2; half++) {
        #pragma unroll
        for (int r = 0; r < 4; r++) {
          float v = exp2_(fmaf(acc[2 * ks + half][r], c2, ofs));
          pv[half * 4 + r] = fminf(fmaxf(rintf(v), qlo), qhi) * delta;
        }
      }
      unsigned wa = cvtpk(pv[0], pv[1]);
      unsigned wb = cvtpk(pv[2], pv[3]);
      unsigned wc = cvtpk(pv[4], pv[5]);
      unsigned wd = cvtpk(pv[6], pv[7]);
      pl32swap(wa, wc);
      pl16swap(wa, wc);
      pl32swap(wb, wd);
      pl16swap(wb, wd);
      uint4 w = make_uint4(wa, wb, wc, wd);
      bf16x8 pa = *(bf16x8*)&w;
      bf16x8 b0 = *(const bf16x8*)&VsL[((ks * 2 + 0) * 64 + quad * 16 + lr) * 8];
      bf16x8 b1 = *(const bf16x8*)&VsL[((ks * 2 + 1) * 64 + quad * 16 + lr) * 8];
      o0 = __builtin_amdgcn_mfma_f32_16x16x32_bf16(pa, b0, o0, 0, 0, 0);
      o1 = __builtin_amdgcn_mfma_f32_16x16x32_bf16(pa, b1, o1, 0, 0, 0);
    }
    #pragma unroll
    for (int r = 0; r < 4; r++) {
      int n = row0 + g * 64 + wid * 16 + quad * 4 + r;
      size_t base = ((size_t)(b * 4096) + n) * 256 + h * 32;
      attn_out[base + lr] = f2bf(o0[r]);
      attn_out[base + 16 + lr] = f2bf(o1[r]);
    }
  }
}

extern "C" void kernel_launch(void* const* d_in, const int* in_sizes, int n_in,
                              void* d_out, int out_size, void* d_ws, size_t ws_size,
                              hipStream_t stream) {
  const float* x      = (const float*)d_in[0];
  const float* q_w    = (const float*)d_in[1];
  const float* q_b    = (const float*)d_in[2];
  const float* kv_w   = (const float*)d_in[3];
  const float* kv_b   = (const float*)d_in[4];
  const float* sr_w   = (const float*)d_in[5];
  const float* sr_b   = (const float*)d_in[6];
  const float* norm_g = (const float*)d_in[7];
  const float* norm_b = (const float*)d_in[8];
  const float* proj_w = (const float*)d_in[9];
  const float* proj_b = (const float*)d_in[10];
  float* out = (float*)d_out;

  char* ws = (char*)d_ws;
  float* scal = (float*)ws;
  unsigned short* q_wq    = (unsigned short*)(ws + 256);       // 128 KB
  unsigned short* kv_wq   = (unsigned short*)(ws + 131328);    // 256 KB
  unsigned short* proj_wq = (unsigned short*)(ws + 393472);    // 128 KB
  unsigned short* sr_wq   = (unsigned short*)(ws + 524544);    // 2 MB   -> 2621696
  unsigned short* xn      = (unsigned short*)(ws + 2621696);   // 1 MB   -> 3670272
  unsigned short* kqu     = (unsigned short*)(ws + 7864576);   // 1 MB (bf16 k, UNquantized)
  unsigned short* vqtu    = (unsigned short*)(ws + 8913152);   // 1 MB (bf16 v^T, UNquantized)
  float2*         rowstats= (float2*)(ws + 9961728);           // 2 MB   -> 12058880
  float*          convp   = (float*)(ws + 12058880);           // 8 MB (4 partials)
  unsigned short* attn_o  = (unsigned short*)(ws + 12058880);  // over convp (dead after k_ln); 16 MB
  float2*         pstat   = (float2*)(ws + 28836096);          // 16 KB
  unsigned short* qq      = (unsigned short*)(ws + 45613312);  // 16 MB (bf16 q, UNquantized)
  unsigned short* xb      = (unsigned short*)(ws + 62390528);  // 16 MB (x as bf16) -> 79167744
  float*          wredW   = (float*)(ws + 79167744);           // 1 KB (absmax partials)
  float*          wredG   = (float*)(ws + 79168768);           // 12 KB (gemm amax partials)

  k_absmax4<<<dim3(64, 4), 256, 0, stream>>>(q_w, kv_w, sr_w, proj_w, wredW);
  k_redW<<<1, 256, 0, stream>>>(wredW, scal);
  // weight quant + x->bf16 cast
  k_quantw<<<4096, 256, 0, stream>>>(q_w, kv_w, proj_w, sr_w, x,
                                     q_wq, kv_wq, proj_wq, sr_wq, xb, scal);
  // conv GEMM (im2col fused, split-K=4, XCD-swizzled): 2048x256x4096
  k_conv_sk<<<512, 256, 0, stream>>>(xb, sr_wq, convp);
  k_ln<<<2048, 256, 0, stream>>>(convp, sr_b, norm_g, norm_b, xn);
  // FUSED kv-GEMM (256 blocks) + q-GEMM (512 blocks); per-wave amax -> wredG
  k_gemm_qkv<<<768, 256, 0, stream>>>(xn, kv_wq, kv_b, xb, q_wq, q_b,
                                      kqu, vqtu, qq, wredG);
  k_redG<<<1, 256, 0, stream>>>(wredG, scal);
  k_attn1<<<dim3(32, 64), 256, 0, stream>>>(qq, kqu, rowstats, scal, pstat);
  k_pminmax<<<1, 256, 0, stream>>>(pstat, scal);
  k_attn2<<<dim3(32, 64), 256, 0, stream>>>(qq, kqu, vqtu, scal, rowstats, attn_o);
  // proj GEMM: 32768x256x256, 128-tile, XCD-swizzled
  k_gemm128<<<512, 256, 0, stream>>>(attn_o, proj_wq, proj_b, out);
}

// Round 13
// 235.359 us; speedup vs baseline: 1.0063x; 1.0063x over previous
//
#include <hip/hip_runtime.h>
#include <stdint.h>

typedef float f32x4 __attribute__((ext_vector_type(4)));
typedef __bf16 bf16x8 __attribute__((ext_vector_type(8)));

#define DEV __device__ __forceinline__

DEV unsigned short f2bf(float f) {
  unsigned u = __float_as_uint(f);
  u += 0x7FFFu + ((u >> 16) & 1u);   // round-to-nearest-even
  return (unsigned short)(u >> 16);
}

DEV float exp2_(float x) {
#if __has_builtin(__builtin_amdgcn_exp2f)
  return __builtin_amdgcn_exp2f(x);   // raw v_exp_f32; args in [-60,0] => normal range
#else
  return exp2f(x);
#endif
}

// pack two f32 -> one u32 of 2 bf16 (RNE), single instruction
DEV unsigned cvtpk(float lo, float hi) {
  unsigned r;
  asm("v_cvt_pk_bf16_f32 %0, %1, %2" : "=v"(r) : "v"(lo), "v"(hi));
  return r;
}

// a' = {a.lo32, b.lo32}; b' = {a.hi32, b.hi32}
DEV void pl32swap(unsigned &a, unsigned &b) {
#if __has_builtin(__builtin_amdgcn_permlane32_swap)
  auto r = __builtin_amdgcn_permlane32_swap(a, b, false, false);
  a = r[0]; b = r[1];
#else
  asm("v_permlane32_swap_b32 %0, %1" : "+v"(a), "+v"(b));
#endif
}

// rows = 16-lane groups: a' = {a.r0, b.r0, a.r2, b.r2}; b' = {a.r1, b.r1, a.r3, b.r3}
DEV void pl16swap(unsigned &a, unsigned &b) {
#if __has_builtin(__builtin_amdgcn_permlane16_swap)
  auto r = __builtin_amdgcn_permlane16_swap(a, b, false, false);
  a = r[0]; b = r[1];
#else
  asm("v_permlane16_swap_b32 %0, %1" : "+v"(a), "+v"(b));
#endif
}

// symmetric fake-quant of 8 packed bf16 in-register (deterministic: every
// consumer of the same bytes + same delta produces IDENTICAL results).
DEV uint4 qfrag4(uint4 w, float idq, float dq) {
  unsigned o[4];
  const unsigned* wi = &w.x;
  #pragma unroll
  for (int i = 0; i < 4; i++) {
    float lo = __uint_as_float(wi[i] << 16);
    float hi = __uint_as_float(wi[i] & 0xffff0000u);
    lo = fminf(fmaxf(rintf(lo * idq), -128.f), 127.f) * dq;
    hi = fminf(fmaxf(rintf(hi * idq), -128.f), 127.f) * dq;
    o[i] = cvtpk(lo, hi);
  }
  return make_uint4(o[0], o[1], o[2], o[3]);
}

DEV bf16x8 qfrag(uint4 w, float idq, float dq) {
  uint4 r = qfrag4(w, idq, dq);
  return *(bf16x8*)&r;
}

// per-weight absmax partials: plain stores (NO same-line atomics; R15-R17).
// Block (bx, t) writes wred[t*64 + bx]; consumers re-reduce (cross-dispatch
// visibility is guaranteed at kernel boundaries).
__global__ __launch_bounds__(256) void k_absmax4(const float* w0, const float* w1,
                                                 const float* w2, const float* w3,
                                                 float* wred) {
  const float* srcs[4] = {w0, w1, w2, w3};
  const int ns[4] = {65536, 131072, 1048576, 65536};
  int t = blockIdx.y;
  const float* src = srcs[t];
  int n = ns[t];
  float m = 0.f;
  for (int i = blockIdx.x * 256 + threadIdx.x; i < n; i += gridDim.x * 256)
    m = fmaxf(m, fabsf(src[i]));
  #pragma unroll
  for (int d = 1; d < 64; d <<= 1) m = fmaxf(m, __shfl_xor(m, d, 64));
  __shared__ float red[4];
  if ((threadIdx.x & 63) == 0) red[threadIdx.x >> 6] = m;
  __syncthreads();
  if (threadIdx.x == 0) {
    m = fmaxf(fmaxf(red[0], red[1]), fmaxf(red[2], red[3]));
    wred[t * 64 + blockIdx.x] = m;
  }
}

// fused weight quant + x->bf16 cast (grid.x = 4096). R21: reduces wred[4][64]
// in-prologue (k_redW launch deleted; fmax is exact => bit-identical).
__global__ __launch_bounds__(256) void k_quantw(const float* qw, const float* kvw,
                                                const float* prw, const float* srw,
                                                const float* xf,
                                                unsigned short* qo, unsigned short* kvo,
                                                unsigned short* pro, unsigned short* sro,
                                                unsigned short* xbo,
                                                const float* __restrict__ wred) {
  __shared__ float sred[4];
  {
    float v = wred[threadIdx.x];          // 256 = 4 weights x 64 partials
    #pragma unroll
    for (int d = 1; d < 64; d <<= 1) v = fmaxf(v, __shfl_xor(v, d, 64));
    if ((threadIdx.x & 63) == 0) sred[threadIdx.x >> 6] = v;
    __syncthreads();
  }
  float d_q  = sred[0] / 127.f + 1e-8f;
  float d_kv = sred[1] / 127.f + 1e-8f;
  float d_sr = sred[2] / 127.f + 1e-8f;
  float d_pr = sred[3] / 127.f + 1e-8f;
  int bx = blockIdx.x;
  int tid = bx * 256 + threadIdx.x;
  {
    int oo = tid >> 12;
    int rem = tid & 4095;
    int khkw = rem >> 8;
    int i = rem & 255;
    float x = srw[oo * 4096 + i * 16 + khkw];
    sro[tid] = f2bf(fminf(fmaxf(rintf(x / d_sr), -128.f), 127.f) * d_sr);
  }
  {
    // x cast: 8 contiguous f32 -> 8 bf16 per thread
    const float4* xs = (const float4*)(xf + (size_t)tid * 8);
    float4 v0 = xs[0], v1 = xs[1];
    unsigned w0 = ((unsigned)f2bf(v0.y) << 16) | f2bf(v0.x);
    unsigned w1 = ((unsigned)f2bf(v0.w) << 16) | f2bf(v0.z);
    unsigned w2 = ((unsigned)f2bf(v1.y) << 16) | f2bf(v1.x);
    unsigned w3 = ((unsigned)f2bf(v1.w) << 16) | f2bf(v1.z);
    *(uint4*)(xbo + (size_t)tid * 8) = make_uint4(w0, w1, w2, w3);
  }
  if (bx < 512) {
    kvo[tid] = f2bf(fminf(fmaxf(rintf(kvw[tid] / d_kv), -128.f), 127.f) * d_kv);
  }
  if (bx < 256) {
    qo[tid] = f2bf(fminf(fmaxf(rintf(qw[tid] / d_q), -128.f), 127.f) * d_q);
    pro[tid] = f2bf(fminf(fmaxf(rintf(prw[tid] / d_pr), -128.f), 127.f) * d_pr);
  }
}

// ---- FUSED kv-GEMM + q-GEMM, one dispatch (768 blocks) ----
// Per-wave amax -> wredG[bid*4+wid] (plain stores; NO same-line atomics).
__global__ __launch_bounds__(256) void k_gemm_qkv(const unsigned short* __restrict__ xnrm,
                                                  const unsigned short* __restrict__ kvw,
                                                  const float* __restrict__ kvb,
                                                  const unsigned short* __restrict__ xb,
                                                  const unsigned short* __restrict__ qw,
                                                  const float* __restrict__ qb,
                                                  unsigned short* __restrict__ kqu,
                                                  unsigned short* __restrict__ vqtu,
                                                  unsigned short* __restrict__ qq,
                                                  float* __restrict__ wredG) {
  __shared__ unsigned short smem[18432];  // 36.9 KB union
  const int tid = threadIdx.x;
  const int wid = tid >> 6, lane = tid & 63;
  const int quad = lane >> 4, lr = lane & 15;
  const int wm = wid >> 1, wn = wid & 1;
  if (blockIdx.x < 256) {
    // ---------------- kv GEMM ----------------
    unsigned short* As = smem;            // 64*136
    unsigned short* Bs = smem + 8704;     // 64*136
    const int n0 = (blockIdx.x & 7) * 64, m0 = (blockIdx.x >> 3) * 64;
    f32x4 acc[2][2] = {};
    for (int kb = 0; kb < 256; kb += 128) {
      __syncthreads();
      #pragma unroll
      for (int i = 0; i < 4; i++) {
        int c = i * 256 + tid;
        int row = c >> 4, cu = (c & 15) * 8;
        *(uint4*)&As[row * 136 + cu] = *(const uint4*)(xnrm + (size_t)(m0 + row) * 256 + kb + cu);
        *(uint4*)&Bs[row * 136 + cu] = *(const uint4*)(kvw + (size_t)(n0 + row) * 256 + kb + cu);
      }
      __syncthreads();
      #pragma unroll
      for (int kc = 0; kc < 4; kc++) {
        bf16x8 af0 = *(const bf16x8*)&As[(wm * 32 + lr) * 136 + kc * 32 + quad * 8];
        bf16x8 af1 = *(const bf16x8*)&As[(wm * 32 + 16 + lr) * 136 + kc * 32 + quad * 8];
        bf16x8 bf0 = *(const bf16x8*)&Bs[(wn * 32 + lr) * 136 + kc * 32 + quad * 8];
        bf16x8 bf1 = *(const bf16x8*)&Bs[(wn * 32 + 16 + lr) * 136 + kc * 32 + quad * 8];
        acc[0][0] = __builtin_amdgcn_mfma_f32_16x16x32_bf16(af0, bf0, acc[0][0], 0, 0, 0);
        acc[0][1] = __builtin_amdgcn_mfma_f32_16x16x32_bf16(af0, bf1, acc[0][1], 0, 0, 0);
        acc[1][0] = __builtin_amdgcn_mfma_f32_16x16x32_bf16(af1, bf0, acc[1][0], 0, 0, 0);
        acc[1][1] = __builtin_amdgcn_mfma_f32_16x16x32_bf16(af1, bf1, acc[1][1], 0, 0, 0);
      }
    }
    float amax = 0.f;
    #pragma unroll
    for (int mi = 0; mi < 2; mi++)
      #pragma unroll
      for (int ni = 0; ni < 2; ni++) {
        int col = n0 + wn * 32 + ni * 16 + lr;
        float bv = kvb[col];
        #pragma unroll
        for (int r = 0; r < 4; r++) {
          int row = m0 + wm * 32 + mi * 16 + quad * 4 + r;
          float v = acc[mi][ni][r] + bv;
          int b = row >> 8, n2 = row & 255;
          int h = (col >> 5) & 7, j = col & 31;
          if (col < 256)
            kqu[((size_t)((b * 8 + h) * 256 + n2)) * 32 + j] = f2bf(v);
          else
            vqtu[((size_t)((b * 8 + h) * 32 + j)) * 256 + n2] = f2bf(v);
          amax = fmaxf(amax, fabsf(v));
        }
      }
    #pragma unroll
    for (int d = 1; d < 64; d <<= 1) amax = fmaxf(amax, __shfl_xor(amax, d, 64));
    if (lane == 0) wredG[(blockIdx.x << 2) | wid] = amax;
  } else {
    // ---------------- q GEMM (XCD-swizzled 128x128) ----------------
    unsigned short* As = smem;            // 128*72
    unsigned short* Bs = smem + 9216;     // 128*72
    const int id = blockIdx.x - 256;
    const int xcd = id & 7, idx = id >> 3;          // 64 blocks per XCD
    const int mt = xcd * 32 + (idx >> 1), nt = idx & 1;
    const int m0 = mt * 128, n0 = nt * 128;
    f32x4 acc[4][4] = {};
    for (int kb = 0; kb < 256; kb += 64) {
      __syncthreads();
      #pragma unroll
      for (int i = 0; i < 4; i++) {
        int c = i * 256 + tid;
        int row = c >> 3, cu = (c & 7) * 8;
        *(uint4*)&As[row * 72 + cu] = *(const uint4*)(xb + (size_t)(m0 + row) * 256 + kb + cu);
        *(uint4*)&Bs[row * 72 + cu] = *(const uint4*)(qw + (size_t)(n0 + row) * 256 + kb + cu);
      }
      __syncthreads();
      #pragma unroll
      for (int kc = 0; kc < 2; kc++) {
        bf16x8 af[4], bf[4];
        #pragma unroll
        for (int mi = 0; mi < 4; mi++)
          af[mi] = *(const bf16x8*)&As[(wm * 64 + mi * 16 + lr) * 72 + kc * 32 + quad * 8];
        #pragma unroll
        for (int ni = 0; ni < 4; ni++)
          bf[ni] = *(const bf16x8*)&Bs[(wn * 64 + ni * 16 + lr) * 72 + kc * 32 + quad * 8];
        #pragma unroll
        for (int mi = 0; mi < 4; mi++)
          #pragma unroll
          for (int ni = 0; ni < 4; ni++)
            acc[mi][ni] = __builtin_amdgcn_mfma_f32_16x16x32_bf16(af[mi], bf[ni], acc[mi][ni], 0, 0, 0);
      }
    }
    float amax = 0.f;
    #pragma unroll
    for (int mi = 0; mi < 4; mi++)
      #pragma unroll
      for (int ni = 0; ni < 4; ni++) {
        int col = n0 + wn * 64 + ni * 16 + lr;
        float bv = qb[col];
        #pragma unroll
        for (int r = 0; r < 4; r++) {
          int row = m0 + wm * 64 + mi * 16 + quad * 4 + r;
          float v = acc[mi][ni][r] + bv;
          int b = row >> 12, nn = row & 4095;
          int h = col >> 5, j = col & 31;
          qq[((size_t)(b * 8 + h) * 4096 + nn) * 32 + j] = f2bf(v);
          amax = fmaxf(amax, fabsf(v));
        }
      }
    #pragma unroll
    for (int d = 1; d < 64; d <<= 1) amax = fmaxf(amax, __shfl_xor(amax, d, 64));
    if (lane == 0) wredG[(blockIdx.x << 2) | wid] = amax;
  }
}

// per-block wredG[3072] reduction (exact fmax => order-independent, identical
// across all consumer blocks): mk=kmax, mv=vmax, mq=qmax.
DEV void redG_block(const float* __restrict__ wredG, int tid, float* sred,
                    float& dk, float& dv, float& dq) {
  int wid = tid >> 6, lane = tid & 63;
  float mk = 0.f, mv = 0.f, mq = 0.f;
  #pragma unroll
  for (int i = 0; i < 12; i++) {
    int idx = tid + i * 256;
    float v = wredG[idx];
    int bid = idx >> 2;
    if (bid < 256) {
      if ((bid & 7) < 4) mk = fmaxf(mk, v);
      else               mv = fmaxf(mv, v);
    } else {
      mq = fmaxf(mq, v);
    }
  }
  #pragma unroll
  for (int d = 1; d < 64; d <<= 1) {
    mk = fmaxf(mk, __shfl_xor(mk, d, 64));
    mv = fmaxf(mv, __shfl_xor(mv, d, 64));
    mq = fmaxf(mq, __shfl_xor(mq, d, 64));
  }
  if (lane == 0) { sred[wid] = mk; sred[4 + wid] = mv; sred[8 + wid] = mq; }
  __syncthreads();
  dk = fmaxf(fmaxf(sred[0], sred[1]), fmaxf(sred[2], sred[3])) / 127.f + 1e-8f;
  dv = fmaxf(fmaxf(sred[4], sred[5]), fmaxf(sred[6], sred[7])) / 127.f + 1e-8f;
  dq = fmaxf(fmaxf(sred[8], sred[9]), fmaxf(sred[10], sred[11])) / 127.f + 1e-8f;
}

// ---- 128x128-tile GEMM (proj): f32 C out, XCD-swizzled ----
__global__ __launch_bounds__(256) void k_gemm128(const unsigned short* __restrict__ Ab,
                                                 const unsigned short* __restrict__ W,
                                                 const float* __restrict__ bias,
                                                 float* __restrict__ C) {
  __shared__ unsigned short As[128 * 72];
  __shared__ unsigned short Bs[128 * 72];
  const int id = blockIdx.x;
  const int xcd = id & 7, idx = id >> 3;
  const int mt = xcd * 32 + (idx >> 1), nt = idx & 1;
  const int m0 = mt * 128, n0 = nt * 128;
  const int tid = threadIdx.x;
  const int wid = tid >> 6, lane = tid & 63;
  const int quad = lane >> 4, lr = lane & 15;
  const int wm = wid >> 1, wn = wid & 1;
  f32x4 acc[4][4] = {};
  for (int kb = 0; kb < 256; kb += 64) {
    __syncthreads();
    #pragma unroll
    for (int i = 0; i < 4; i++) {
      int c = i * 256 + tid;
      int row = c >> 3, cu = (c & 7) * 8;
      *(uint4*)&As[row * 72 + cu] = *(const uint4*)(Ab + (size_t)(m0 + row) * 256 + kb + cu);
      *(uint4*)&Bs[row * 72 + cu] = *(const uint4*)(W + (size_t)(n0 + row) * 256 + kb + cu);
    }
    __syncthreads();
    #pragma unroll
    for (int kc = 0; kc < 2; kc++) {
      bf16x8 af[4], bf[4];
      #pragma unroll
      for (int mi = 0; mi < 4; mi++)
        af[mi] = *(const bf16x8*)&As[(wm * 64 + mi * 16 + lr) * 72 + kc * 32 + quad * 8];
      #pragma unroll
      for (int ni = 0; ni < 4; ni++)
        bf[ni] = *(const bf16x8*)&Bs[(wn * 64 + ni * 16 + lr) * 72 + kc * 32 + quad * 8];
      #pragma unroll
      for (int mi = 0; mi < 4; mi++)
        #pragma unroll
        for (int ni = 0; ni < 4; ni++)
          acc[mi][ni] = __builtin_amdgcn_mfma_f32_16x16x32_bf16(af[mi], bf[ni], acc[mi][ni], 0, 0, 0);
    }
  }
  #pragma unroll
  for (int mi = 0; mi < 4; mi++)
    #pragma unroll
    for (int ni = 0; ni < 4; ni++) {
      int col = n0 + wn * 64 + ni * 16 + lr;
      float bv = bias[col];
      #pragma unroll
      for (int r = 0; r < 4; r++) {
        int row = m0 + wm * 64 + mi * 16 + quad * 4 + r;
        C[(size_t)row * 256 + col] = acc[mi][ni][r] + bv;
      }
    }
}

// ---- conv GEMM: 2048x256xK4096, split-K=4, im2col fused (bf16 x); flat grid 512
__global__ __launch_bounds__(256) void k_conv_sk(const unsigned short* __restrict__ xb,
                                                 const unsigned short* __restrict__ W,
                                                 float* __restrict__ C) {
  __shared__ unsigned short As[64 * 136];
  __shared__ unsigned short Bs[64 * 136];
  const int id = blockIdx.x;
  const int xcd = id & 7, idx = id >> 3;
  const int a = idx >> 2, nt = idx & 3;
  const int ag = xcd * 16 + a;
  const int mt = ag & 31, z = ag >> 5;
  const int m0 = mt * 64, n0 = nt * 64;
  const int kOff = z * 1024;
  C += (size_t)z * 2048 * 256;
  const int tid = threadIdx.x;
  const int wid = tid >> 6, lane = tid & 63;
  const int quad = lane >> 4, lr = lane & 15;
  const int wm = wid >> 1, wn = wid & 1;
  f32x4 acc[2][2] = {};
  for (int kb = 0; kb < 1024; kb += 128) {
    __syncthreads();
    #pragma unroll
    for (int i = 0; i < 4; i++) {
      int c = i * 256 + tid;
      int row = c >> 4, cu = (c & 15) * 8;
      int kk = kOff + kb + cu;
      int m = m0 + row;
      int b = m >> 8, p = m & 255, ph = p >> 4, pw = p & 15;
      int q = kk >> 8, ii = kk & 255;
      int n = (ph * 4 + (q >> 2)) * 64 + pw * 4 + (q & 3);
      *(uint4*)&As[row * 136 + cu] = *(const uint4*)(xb + ((size_t)(b * 4096 + n) * 256 + ii));
      *(uint4*)&Bs[row * 136 + cu] = *(const uint4*)(W + (size_t)(n0 + row) * 4096 + kk);
    }
    __syncthreads();
    #pragma unroll
    for (int kc = 0; kc < 4; kc++) {
      bf16x8 af0 = *(const bf16x8*)&As[(wm * 32 + lr) * 136 + kc * 32 + quad * 8];
      bf16x8 af1 = *(const bf16x8*)&As[(wm * 32 + 16 + lr) * 136 + kc * 32 + quad * 8];
      bf16x8 bf0 = *(const bf16x8*)&Bs[(wn * 32 + lr) * 136 + kc * 32 + quad * 8];
      bf16x8 bf1 = *(const bf16x8*)&Bs[(wn * 32 + 16 + lr) * 136 + kc * 32 + quad * 8];
      acc[0][0] = __builtin_amdgcn_mfma_f32_16x16x32_bf16(af0, bf0, acc[0][0], 0, 0, 0);
      acc[0][1] = __builtin_amdgcn_mfma_f32_16x16x32_bf16(af0, bf1, acc[0][1], 0, 0, 0);
      acc[1][0] = __builtin_amdgcn_mfma_f32_16x16x32_bf16(af1, bf0, acc[1][0], 0, 0, 0);
      acc[1][1] = __builtin_amdgcn_mfma_f32_16x16x32_bf16(af1, bf1, acc[1][1], 0, 0, 0);
    }
  }
  #pragma unroll
  for (int mi = 0; mi < 2; mi++)
    #pragma unroll
    for (int ni = 0; ni < 2; ni++) {
      int col = n0 + wn * 32 + ni * 16 + lr;
      #pragma unroll
      for (int r = 0; r < 4; r++) {
        int row = m0 + wm * 32 + mi * 16 + quad * 4 + r;
        C[(size_t)row * 256 + col] = acc[mi][ni][r];
      }
    }
}

// LayerNorm over C=256; sums 4 split-K conv partials + sr_b first
__global__ __launch_bounds__(256) void k_ln(const float* __restrict__ convp, const float* srb,
                                            const float* g, const float* bb,
                                            unsigned short* __restrict__ xn) {
  int row = blockIdx.x, c = threadIdx.x;
  float v = srb[c];
  #pragma unroll
  for (int s = 0; s < 4; s++) v += convp[s * 524288 + row * 256 + c];
  __shared__ float red[4];
  float s = v;
  #pragma unroll
  for (int d = 1; d < 64; d <<= 1) s += __shfl_xor(s, d, 64);
  if ((c & 63) == 0) red[c >> 6] = s;
  __syncthreads();
  float mu = (red[0] + red[1] + red[2] + red[3]) * (1.f / 256.f);
  __syncthreads();
  float dv = v - mu;
  float s2 = dv * dv;
  #pragma unroll
  for (int d = 1; d < 64; d <<= 1) s2 += __shfl_xor(s2, d, 64);
  if ((c & 63) == 0) red[c >> 6] = s2;
  __syncthreads();
  float var = (red[0] + red[1] + red[2] + red[3]) * (1.f / 256.f);
  float rs = 1.f / sqrtf(var + 1e-5f);
  xn[row * 256 + c] = f2bf(dv * rs * g[c] + bb[c]);
}

// attention pass 1 (R21): reduces wredG in-prologue (k_redG launch deleted);
// swapped QK^T; K staged lane-major + fake-quant in staging; q quantized
// in-register. Per-block (wmin,wmax) -> pstat (no atomics). Grid 32x64.
__global__ __launch_bounds__(256) void k_attn1(const unsigned short* __restrict__ qq,
                                               const unsigned short* __restrict__ kqu,
                                               float2* __restrict__ rowstats,
                                               const float* __restrict__ wredG,
                                               float2* __restrict__ pstat) {
  __shared__ unsigned short KsL[8192];  // 16 KB: [t(16)][lane(64)] x 8 shorts
  __shared__ float red[12];
  const int bh = blockIdx.y;
  const int row0 = blockIdx.x * 128;
  const int tid = threadIdx.x, wid = tid >> 6, lane = tid & 63, quad = lane >> 4, lr = lane & 15;
  const float c2 = 0.17677669529663687f * 1.4426950408889634f;  // 32^-0.5 * log2(e)
  const unsigned short* kb = kqu + (size_t)bh * 8192;
  float dk, dvv, dq;
  redG_block(wredG, tid, red, dk, dvv, dq);
  float idk = 1.f / dk;
  float idq = 1.f / dq;
  #pragma unroll
  for (int k = 0; k < 4; k++) {
    int cid = k * 256 + tid;                 // 1024 chunks of 16B
    int seg = cid >> 6, lc = cid & 63, qc = lc >> 4, lrc = lc & 15;
    uint4 kw = *(const uint4*)(kb + (seg * 16 + lrc) * 32 + qc * 8);
    *(uint4*)&KsL[cid * 8] = qfrag4(kw, idk, dk);
  }
  __syncthreads();
  float wmin = 1e30f, wmax = 0.f;
  #pragma unroll
  for (int g = 0; g < 2; g++) {
    int rowg = row0 + g * 64 + wid * 16 + lr;
    uint4 qw = *(const uint4*)(qq + ((size_t)bh * 4096 + rowg) * 32 + quad * 8);
    bf16x8 qf = qfrag(qw, idq, dq);
    f32x4 acc[16] = {};
    #pragma unroll
    for (int t = 0; t < 16; t++) {
      bf16x8 kf = *(const bf16x8*)&KsL[(t * 64 + quad * 16 + lr) * 8];
      acc[t] = __builtin_amdgcn_mfma_f32_16x16x32_bf16(kf, qf, acc[t], 0, 0, 0);
    }
    float mxr = -1e30f, mnr = 1e30f;
    #pragma unroll
    for (int t = 0; t < 16; t++)
      #pragma unroll
      for (int r = 0; r < 4; r++) {
        float s = acc[t][r];
        mxr = fmaxf(mxr, s); mnr = fminf(mnr, s);
      }
    #pragma unroll
    for (int d = 16; d < 64; d <<= 1) {
      mxr = fmaxf(mxr, __shfl_xor(mxr, d, 64));
      mnr = fminf(mnr, __shfl_xor(mnr, d, 64));
    }
    float m2 = mxr * c2;
    float l = 0.f;
    #pragma unroll
    for (int t = 0; t < 16; t++)
      #pragma unroll
      for (int r = 0; r < 4; r++)
        l += exp2_(fmaf(acc[t][r], c2, -m2));
    #pragma unroll
    for (int d = 16; d < 64; d <<= 1) l += __shfl_xor(l, d, 64);
    float inv_l = 1.f / l;
    if (lane < 16)
      rowstats[(size_t)bh * 4096 + rowg] = make_float2(m2, inv_l);
    wmax = fmaxf(wmax, inv_l);
    wmin = fminf(wmin, exp2_((mnr - mxr) * c2) * inv_l);
  }
  #pragma unroll
  for (int d = 1; d < 16; d <<= 1) {
    wmax = fmaxf(wmax, __shfl_xor(wmax, d, 64));
    wmin = fminf(wmin, __shfl_xor(wmin, d, 64));
  }
  if (lane == 0) { red[wid] = wmin; red[4 + wid] = wmax; }
  __syncthreads();
  if (tid == 0) {
    float mn = fminf(fminf(red[0], red[1]), fminf(red[2], red[3]));
    float mx = fmaxf(fmaxf(red[4], red[5]), fmaxf(red[6], red[7]));
    pstat[blockIdx.y * 32 + blockIdx.x] = make_float2(mn, mx);
  }
}

// attention pass 2 (R21): reduces wredG AND pstat in-prologue (k_redG +
// k_pminmax launches deleted; fmin/fmax exact => identical across blocks);
// swapped-QK in-register softmax/quant; K/V staged lane-major + fake-quant.
__global__ __launch_bounds__(256) void k_attn2(const unsigned short* __restrict__ qq,
                                               const unsigned short* __restrict__ kqu,
                                               const unsigned short* __restrict__ vqtu,
                                               const float* __restrict__ wredG,
                                               const float2* __restrict__ pstat,
                                               const float2* __restrict__ rowstats,
                                               unsigned short* __restrict__ attn_out) {
  __shared__ unsigned short KsL[8192];  // 16 KB: [t(16)][lane(64)] chunks
  __shared__ unsigned short VsL[8192];  // 16 KB: [ks*2+half(16)][lane(64)] chunks
  __shared__ float red[20];
  const int bh = blockIdx.y, b = bh >> 3, h = bh & 7;
  const int row0 = blockIdx.x * 128;
  const int tid = threadIdx.x, wid = tid >> 6, lane = tid & 63, quad = lane >> 4, lr = lane & 15;
  const float c2 = 0.17677669529663687f * 1.4426950408889634f;
  const unsigned short* kb = kqu + (size_t)bh * 8192;
  const unsigned short* vb = vqtu + (size_t)bh * 8192;
  // prologue reductions: wredG -> dk,dv,dq ; pstat -> pmin,pmax
  float dk, dv, dq;
  {
    float mn = 1e30f, mx = 0.f;
    #pragma unroll
    for (int i = 0; i < 8; i++) {
      float2 v = pstat[tid + i * 256];
      mn = fminf(mn, v.x); mx = fmaxf(mx, v.y);
    }
    #pragma unroll
    for (int d = 1; d < 64; d <<= 1) {
      mn = fminf(mn, __shfl_xor(mn, d, 64));
      mx = fmaxf(mx, __shfl_xor(mx, d, 64));
    }
    if (lane == 0) { red[12 + wid] = mn; red[16 + wid] = mx; }
    redG_block(wredG, tid, red, dk, dv, dq);  // includes the __syncthreads
  }
  float pmin = fminf(fminf(red[12], red[13]), fminf(red[14], red[15]));
  float pmax = fmaxf(fmaxf(red[16], red[17]), fmaxf(red[18], red[19]));
  float idk = 1.f / dk;
  float idv = 1.f / dv;
  float idq = 1.f / dq;
  #pragma unroll
  for (int k = 0; k < 4; k++) {
    int cid = k * 256 + tid;
    int seg = cid >> 6, lc = cid & 63, qc = lc >> 4, lrc = lc & 15;
    uint4 kw = *(const uint4*)(kb + (seg * 16 + lrc) * 32 + qc * 8);
    *(uint4*)&KsL[cid * 8] = qfrag4(kw, idk, dk);
    uint4 vw = *(const uint4*)(vb + ((seg & 1) * 16 + lrc) * 256 + (seg >> 1) * 32 + qc * 8);
    *(uint4*)&VsL[cid * 8] = qfrag4(vw, idv, dv);
  }
  float delta = (pmax - pmin) / 255.f + 1e-8f;
  float zp = rintf(-pmin / delta);
  float qlo = -zp, qhi = 255.f - zp;
  __syncthreads();
  #pragma unroll
  for (int g = 0; g < 2; g++) {
    int rowg = row0 + g * 64 + wid * 16 + lr;
    uint4 qw = *(const uint4*)(qq + ((size_t)bh * 4096 + rowg) * 32 + quad * 8);
    bf16x8 qf = qfrag(qw, idq, dq);
    float2 st = rowstats[(size_t)bh * 4096 + rowg];
    f32x4 acc[16] = {};
    #pragma unroll
    for (int t = 0; t < 16; t++) {
      bf16x8 kf = *(const bf16x8*)&KsL[(t * 64 + quad * 16 + lr) * 8];
      acc[t] = __builtin_amdgcn_mfma_f32_16x16x32_bf16(kf, qf, acc[t], 0, 0, 0);
    }
    float ofs = __log2f(st.y / delta) - st.x;
    f32x4 o0 = {}, o1 = {};
    #pragma unroll
    for (int ks = 0; ks < 8; ks++) {
      float pv[8];
      #pragma unroll
      for (int half = 0; half < 2; half++) {
        #pragma unroll
        for (int r = 0; r < 4; r++) {
          float v = exp2_(fmaf(acc[2 * ks + half][r], c2, ofs));
          pv[half * 4 + r] = fminf(fmaxf(rintf(v), qlo), qhi) * delta;
        }
      }
      unsigned wa = cvtpk(pv[0], pv[1]);
      unsigned wb = cvtpk(pv[2], pv[3]);
      unsigned wc = cvtpk(pv[4], pv[5]);
      unsigned wd = cvtpk(pv[6], pv[7]);
      pl32swap(wa, wc);
      pl16swap(wa, wc);
      pl32swap(wb, wd);
      pl16swap(wb, wd);
      uint4 w = make_uint4(wa, wb, wc, wd);
      bf16x8 pa = *(bf16x8*)&w;
      bf16x8 b0 = *(const bf16x8*)&VsL[((ks * 2 + 0) * 64 + quad * 16 + lr) * 8];
      bf16x8 b1 = *(const bf16x8*)&VsL[((ks * 2 + 1) * 64 + quad * 16 + lr) * 8];
      o0 = __builtin_amdgcn_mfma_f32_16x16x32_bf16(pa, b0, o0, 0, 0, 0);
      o1 = __builtin_amdgcn_mfma_f32_16x16x32_bf16(pa, b1, o1, 0, 0, 0);
    }
    #pragma unroll
    for (int r = 0; r < 4; r++) {
      int n = row0 + g * 64 + wid * 16 + quad * 4 + r;
      size_t base = ((size_t)(b * 4096) + n) * 256 + h * 32;
      attn_out[base + lr] = f2bf(o0[r]);
      attn_out[base + 16 + lr] = f2bf(o1[r]);
    }
  }
}

extern "C" void kernel_launch(void* const* d_in, const int* in_sizes, int n_in,
                              void* d_out, int out_size, void* d_ws, size_t ws_size,
                              hipStream_t stream) {
  const float* x      = (const float*)d_in[0];
  const float* q_w    = (const float*)d_in[1];
  const float* q_b    = (const float*)d_in[2];
  const float* kv_w   = (const float*)d_in[3];
  const float* kv_b   = (const float*)d_in[4];
  const float* sr_w   = (const float*)d_in[5];
  const float* sr_b   = (const float*)d_in[6];
  const float* norm_g = (const float*)d_in[7];
  const float* norm_b = (const float*)d_in[8];
  const float* proj_w = (const float*)d_in[9];
  const float* proj_b = (const float*)d_in[10];
  float* out = (float*)d_out;

  char* ws = (char*)d_ws;
  unsigned short* q_wq    = (unsigned short*)(ws + 256);       // 128 KB
  unsigned short* kv_wq   = (unsigned short*)(ws + 131328);    // 256 KB
  unsigned short* proj_wq = (unsigned short*)(ws + 393472);    // 128 KB
  unsigned short* sr_wq   = (unsigned short*)(ws + 524544);    // 2 MB   -> 2621696
  unsigned short* xn      = (unsigned short*)(ws + 2621696);   // 1 MB   -> 3670272
  unsigned short* kqu     = (unsigned short*)(ws + 7864576);   // 1 MB (bf16 k, UNquantized)
  unsigned short* vqtu    = (unsigned short*)(ws + 8913152);   // 1 MB (bf16 v^T, UNquantized)
  float2*         rowstats= (float2*)(ws + 9961728);           // 2 MB   -> 12058880
  float*          convp   = (float*)(ws + 12058880);           // 8 MB (4 partials)
  unsigned short* attn_o  = (unsigned short*)(ws + 12058880);  // over convp (dead after k_ln); 16 MB
  float2*         pstat   = (float2*)(ws + 28836096);          // 16 KB
  unsigned short* qq      = (unsigned short*)(ws + 45613312);  // 16 MB (bf16 q, UNquantized)
  unsigned short* xb      = (unsigned short*)(ws + 62390528);  // 16 MB (x as bf16) -> 79167744
  float*          wredW   = (float*)(ws + 79167744);           // 1 KB (absmax partials)
  float*          wredG   = (float*)(ws + 79168768);           // 12 KB (gemm amax partials)

  k_absmax4<<<dim3(64, 4), 256, 0, stream>>>(q_w, kv_w, sr_w, proj_w, wredW);
  // weight quant + x->bf16 cast (reduces wredW in-prologue)
  k_quantw<<<4096, 256, 0, stream>>>(q_w, kv_w, proj_w, sr_w, x,
                                     q_wq, kv_wq, proj_wq, sr_wq, xb, wredW);
  // conv GEMM (im2col fused, split-K=4, XCD-swizzled): 2048x256x4096
  k_conv_sk<<<512, 256, 0, stream>>>(xb, sr_wq, convp);
  k_ln<<<2048, 256, 0, stream>>>(convp, sr_b, norm_g, norm_b, xn);
  // FUSED kv-GEMM (256 blocks) + q-GEMM (512 blocks); per-wave amax -> wredG
  k_gemm_qkv<<<768, 256, 0, stream>>>(xn, kv_wq, kv_b, xb, q_wq, q_b,
                                      kqu, vqtu, qq, wredG);
  // attn1 (reduces wredG in-prologue)
  k_attn1<<<dim3(32, 64), 256, 0, stream>>>(qq, kqu, rowstats, wredG, pstat);
  // attn2 (reduces wredG + pstat in-prologue)
  k_attn2<<<dim3(32, 64), 256, 0, stream>>>(qq, kqu, vqtu, wredG, pstat, rowstats, attn_o);
  // proj GEMM: 32768x256x256, 128-tile, XCD-swizzled
  k_gemm128<<<512, 256, 0, stream>>>(attn_o, proj_wq, proj_b, out);
}

// Round 14
// 234.927 us; speedup vs baseline: 1.0082x; 1.0018x over previous
//
#include <hip/hip_runtime.h>
#include <stdint.h>

typedef float f32x4 __attribute__((ext_vector_type(4)));
typedef __bf16 bf16x8 __attribute__((ext_vector_type(8)));

#define DEV __device__ __forceinline__

DEV unsigned short f2bf(float f) {
  unsigned u = __float_as_uint(f);
  u += 0x7FFFu + ((u >> 16) & 1u);   // round-to-nearest-even
  return (unsigned short)(u >> 16);
}

DEV float exp2_(float x) {
#if __has_builtin(__builtin_amdgcn_exp2f)
  return __builtin_amdgcn_exp2f(x);   // raw v_exp_f32; args in [-60,0] => normal range
#else
  return exp2f(x);
#endif
}

// pack two f32 -> one u32 of 2 bf16 (RNE), single instruction
DEV unsigned cvtpk(float lo, float hi) {
  unsigned r;
  asm("v_cvt_pk_bf16_f32 %0, %1, %2" : "=v"(r) : "v"(lo), "v"(hi));
  return r;
}

// a' = {a.lo32, b.lo32}; b' = {a.hi32, b.hi32}
DEV void pl32swap(unsigned &a, unsigned &b) {
#if __has_builtin(__builtin_amdgcn_permlane32_swap)
  auto r = __builtin_amdgcn_permlane32_swap(a, b, false, false);
  a = r[0]; b = r[1];
#else
  asm("v_permlane32_swap_b32 %0, %1" : "+v"(a), "+v"(b));
#endif
}

// rows = 16-lane groups: a' = {a.r0, b.r0, a.r2, b.r2}; b' = {a.r1, b.r1, a.r3, b.r3}
DEV void pl16swap(unsigned &a, unsigned &b) {
#if __has_builtin(__builtin_amdgcn_permlane16_swap)
  auto r = __builtin_amdgcn_permlane16_swap(a, b, false, false);
  a = r[0]; b = r[1];
#else
  asm("v_permlane16_swap_b32 %0, %1" : "+v"(a), "+v"(b));
#endif
}

// symmetric fake-quant of 8 packed bf16 in-register (deterministic: every
// consumer of the same bytes + same delta produces IDENTICAL results).
DEV uint4 qfrag4(uint4 w, float idq, float dq) {
  unsigned o[4];
  const unsigned* wi = &w.x;
  #pragma unroll
  for (int i = 0; i < 4; i++) {
    float lo = __uint_as_float(wi[i] << 16);
    float hi = __uint_as_float(wi[i] & 0xffff0000u);
    lo = fminf(fmaxf(rintf(lo * idq), -128.f), 127.f) * dq;
    hi = fminf(fmaxf(rintf(hi * idq), -128.f), 127.f) * dq;
    o[i] = cvtpk(lo, hi);
  }
  return make_uint4(o[0], o[1], o[2], o[3]);
}

// per-weight absmax partials: plain stores (NO same-line atomics; R15-R17).
// Block (bx, t) writes wred[t*64 + bx]; consumers re-reduce (cross-dispatch
// visibility is guaranteed at kernel boundaries).
__global__ __launch_bounds__(256) void k_absmax4(const float* w0, const float* w1,
                                                 const float* w2, const float* w3,
                                                 float* wred) {
  const float* srcs[4] = {w0, w1, w2, w3};
  const int ns[4] = {65536, 131072, 1048576, 65536};
  int t = blockIdx.y;
  const float* src = srcs[t];
  int n = ns[t];
  float m = 0.f;
  for (int i = blockIdx.x * 256 + threadIdx.x; i < n; i += gridDim.x * 256)
    m = fmaxf(m, fabsf(src[i]));
  #pragma unroll
  for (int d = 1; d < 64; d <<= 1) m = fmaxf(m, __shfl_xor(m, d, 64));
  __shared__ float red[4];
  if ((threadIdx.x & 63) == 0) red[threadIdx.x >> 6] = m;
  __syncthreads();
  if (threadIdx.x == 0) {
    m = fmaxf(fmaxf(red[0], red[1]), fmaxf(red[2], red[3]));
    wred[t * 64 + blockIdx.x] = m;
  }
}

// fused weight quant + x->bf16 cast (grid.x = 4096); reduces wred[4][64]
// in-prologue (fmax is exact => bit-identical across blocks).
__global__ __launch_bounds__(256) void k_quantw(const float* qw, const float* kvw,
                                                const float* prw, const float* srw,
                                                const float* xf,
                                                unsigned short* qo, unsigned short* kvo,
                                                unsigned short* pro, unsigned short* sro,
                                                unsigned short* xbo,
                                                const float* __restrict__ wred) {
  __shared__ float sred[4];
  {
    float v = wred[threadIdx.x];          // 256 = 4 weights x 64 partials
    #pragma unroll
    for (int d = 1; d < 64; d <<= 1) v = fmaxf(v, __shfl_xor(v, d, 64));
    if ((threadIdx.x & 63) == 0) sred[threadIdx.x >> 6] = v;
    __syncthreads();
  }
  float d_q  = sred[0] / 127.f + 1e-8f;
  float d_kv = sred[1] / 127.f + 1e-8f;
  float d_sr = sred[2] / 127.f + 1e-8f;
  float d_pr = sred[3] / 127.f + 1e-8f;
  int bx = blockIdx.x;
  int tid = bx * 256 + threadIdx.x;
  {
    int oo = tid >> 12;
    int rem = tid & 4095;
    int khkw = rem >> 8;
    int i = rem & 255;
    float x = srw[oo * 4096 + i * 16 + khkw];
    sro[tid] = f2bf(fminf(fmaxf(rintf(x / d_sr), -128.f), 127.f) * d_sr);
  }
  {
    // x cast: 8 contiguous f32 -> 8 bf16 per thread
    const float4* xs = (const float4*)(xf + (size_t)tid * 8);
    float4 v0 = xs[0], v1 = xs[1];
    unsigned w0 = ((unsigned)f2bf(v0.y) << 16) | f2bf(v0.x);
    unsigned w1 = ((unsigned)f2bf(v0.w) << 16) | f2bf(v0.z);
    unsigned w2 = ((unsigned)f2bf(v1.y) << 16) | f2bf(v1.x);
    unsigned w3 = ((unsigned)f2bf(v1.w) << 16) | f2bf(v1.z);
    *(uint4*)(xbo + (size_t)tid * 8) = make_uint4(w0, w1, w2, w3);
  }
  if (bx < 512) {
    kvo[tid] = f2bf(fminf(fmaxf(rintf(kvw[tid] / d_kv), -128.f), 127.f) * d_kv);
  }
  if (bx < 256) {
    qo[tid] = f2bf(fminf(fmaxf(rintf(qw[tid] / d_q), -128.f), 127.f) * d_q);
    pro[tid] = f2bf(fminf(fmaxf(rintf(prw[tid] / d_pr), -128.f), 127.f) * d_pr);
  }
}

// ---- FUSED kv-GEMM + q-GEMM, one dispatch (768 blocks) ----
// Per-wave amax -> wredG[bid*4+wid] (plain stores; NO same-line atomics).
__global__ __launch_bounds__(256) void k_gemm_qkv(const unsigned short* __restrict__ xnrm,
                                                  const unsigned short* __restrict__ kvw,
                                                  const float* __restrict__ kvb,
                                                  const unsigned short* __restrict__ xb,
                                                  const unsigned short* __restrict__ qw,
                                                  const float* __restrict__ qb,
                                                  unsigned short* __restrict__ kqu,
                                                  unsigned short* __restrict__ vqtu,
                                                  unsigned short* __restrict__ qq,
                                                  float* __restrict__ wredG) {
  __shared__ unsigned short smem[18432];  // 36.9 KB union
  const int tid = threadIdx.x;
  const int wid = tid >> 6, lane = tid & 63;
  const int quad = lane >> 4, lr = lane & 15;
  const int wm = wid >> 1, wn = wid & 1;
  if (blockIdx.x < 256) {
    // ---------------- kv GEMM ----------------
    unsigned short* As = smem;            // 64*136
    unsigned short* Bs = smem + 8704;     // 64*136
    const int n0 = (blockIdx.x & 7) * 64, m0 = (blockIdx.x >> 3) * 64;
    f32x4 acc[2][2] = {};
    for (int kb = 0; kb < 256; kb += 128) {
      __syncthreads();
      #pragma unroll
      for (int i = 0; i < 4; i++) {
        int c = i * 256 + tid;
        int row = c >> 4, cu = (c & 15) * 8;
        *(uint4*)&As[row * 136 + cu] = *(const uint4*)(xnrm + (size_t)(m0 + row) * 256 + kb + cu);
        *(uint4*)&Bs[row * 136 + cu] = *(const uint4*)(kvw + (size_t)(n0 + row) * 256 + kb + cu);
      }
      __syncthreads();
      #pragma unroll
      for (int kc = 0; kc < 4; kc++) {
        bf16x8 af0 = *(const bf16x8*)&As[(wm * 32 + lr) * 136 + kc * 32 + quad * 8];
        bf16x8 af1 = *(const bf16x8*)&As[(wm * 32 + 16 + lr) * 136 + kc * 32 + quad * 8];
        bf16x8 bf0 = *(const bf16x8*)&Bs[(wn * 32 + lr) * 136 + kc * 32 + quad * 8];
        bf16x8 bf1 = *(const bf16x8*)&Bs[(wn * 32 + 16 + lr) * 136 + kc * 32 + quad * 8];
        acc[0][0] = __builtin_amdgcn_mfma_f32_16x16x32_bf16(af0, bf0, acc[0][0], 0, 0, 0);
        acc[0][1] = __builtin_amdgcn_mfma_f32_16x16x32_bf16(af0, bf1, acc[0][1], 0, 0, 0);
        acc[1][0] = __builtin_amdgcn_mfma_f32_16x16x32_bf16(af1, bf0, acc[1][0], 0, 0, 0);
        acc[1][1] = __builtin_amdgcn_mfma_f32_16x16x32_bf16(af1, bf1, acc[1][1], 0, 0, 0);
      }
    }
    float amax = 0.f;
    #pragma unroll
    for (int mi = 0; mi < 2; mi++)
      #pragma unroll
      for (int ni = 0; ni < 2; ni++) {
        int col = n0 + wn * 32 + ni * 16 + lr;
        float bv = kvb[col];
        #pragma unroll
        for (int r = 0; r < 4; r++) {
          int row = m0 + wm * 32 + mi * 16 + quad * 4 + r;
          float v = acc[mi][ni][r] + bv;
          int b = row >> 8, n2 = row & 255;
          int h = (col >> 5) & 7, j = col & 31;
          if (col < 256)
            kqu[((size_t)((b * 8 + h) * 256 + n2)) * 32 + j] = f2bf(v);
          else
            vqtu[((size_t)((b * 8 + h) * 32 + j)) * 256 + n2] = f2bf(v);
          amax = fmaxf(amax, fabsf(v));
        }
      }
    #pragma unroll
    for (int d = 1; d < 64; d <<= 1) amax = fmaxf(amax, __shfl_xor(amax, d, 64));
    if (lane == 0) wredG[(blockIdx.x << 2) | wid] = amax;
  } else {
    // ---------------- q GEMM (XCD-swizzled 128x128) ----------------
    unsigned short* As = smem;            // 128*72
    unsigned short* Bs = smem + 9216;     // 128*72
    const int id = blockIdx.x - 256;
    const int xcd = id & 7, idx = id >> 3;          // 64 blocks per XCD
    const int mt = xcd * 32 + (idx >> 1), nt = idx & 1;
    const int m0 = mt * 128, n0 = nt * 128;
    f32x4 acc[4][4] = {};
    for (int kb = 0; kb < 256; kb += 64) {
      __syncthreads();
      #pragma unroll
      for (int i = 0; i < 4; i++) {
        int c = i * 256 + tid;
        int row = c >> 3, cu = (c & 7) * 8;
        *(uint4*)&As[row * 72 + cu] = *(const uint4*)(xb + (size_t)(m0 + row) * 256 + kb + cu);
        *(uint4*)&Bs[row * 72 + cu] = *(const uint4*)(qw + (size_t)(n0 + row) * 256 + kb + cu);
      }
      __syncthreads();
      #pragma unroll
      for (int kc = 0; kc < 2; kc++) {
        bf16x8 af[4], bf[4];
        #pragma unroll
        for (int mi = 0; mi < 4; mi++)
          af[mi] = *(const bf16x8*)&As[(wm * 64 + mi * 16 + lr) * 72 + kc * 32 + quad * 8];
        #pragma unroll
        for (int ni = 0; ni < 4; ni++)
          bf[ni] = *(const bf16x8*)&Bs[(wn * 64 + ni * 16 + lr) * 72 + kc * 32 + quad * 8];
        #pragma unroll
        for (int mi = 0; mi < 4; mi++)
          #pragma unroll
          for (int ni = 0; ni < 4; ni++)
            acc[mi][ni] = __builtin_amdgcn_mfma_f32_16x16x32_bf16(af[mi], bf[ni], acc[mi][ni], 0, 0, 0);
      }
    }
    float amax = 0.f;
    #pragma unroll
    for (int mi = 0; mi < 4; mi++)
      #pragma unroll
      for (int ni = 0; ni < 4; ni++) {
        int col = n0 + wn * 64 + ni * 16 + lr;
        float bv = qb[col];
        #pragma unroll
        for (int r = 0; r < 4; r++) {
          int row = m0 + wm * 64 + mi * 16 + quad * 4 + r;
          float v = acc[mi][ni][r] + bv;
          int b = row >> 12, nn = row & 4095;
          int h = col >> 5, j = col & 31;
          qq[((size_t)(b * 8 + h) * 4096 + nn) * 32 + j] = f2bf(v);
          amax = fmaxf(amax, fabsf(v));
        }
      }
    #pragma unroll
    for (int d = 1; d < 64; d <<= 1) amax = fmaxf(amax, __shfl_xor(amax, d, 64));
    if (lane == 0) wredG[(blockIdx.x << 2) | wid] = amax;
  }
}

// per-block wredG[3072] reduction (exact fmax => order-independent, identical
// across all consumer blocks): dk=kmax/127, dv=vmax/127, dq=qmax/127.
DEV void redG_block(const float* __restrict__ wredG, int tid, float* sred,
                    float& dk, float& dv, float& dq) {
  int wid = tid >> 6, lane = tid & 63;
  float mk = 0.f, mv = 0.f, mq = 0.f;
  #pragma unroll
  for (int i = 0; i < 12; i++) {
    int idx = tid + i * 256;
    float v = wredG[idx];
    int bid = idx >> 2;
    if (bid < 256) {
      if ((bid & 7) < 4) mk = fmaxf(mk, v);
      else               mv = fmaxf(mv, v);
    } else {
      mq = fmaxf(mq, v);
    }
  }
  #pragma unroll
  for (int d = 1; d < 64; d <<= 1) {
    mk = fmaxf(mk, __shfl_xor(mk, d, 64));
    mv = fmaxf(mv, __shfl_xor(mv, d, 64));
    mq = fmaxf(mq, __shfl_xor(mq, d, 64));
  }
  if (lane == 0) { sred[wid] = mk; sred[4 + wid] = mv; sred[8 + wid] = mq; }
  __syncthreads();
  dk = fmaxf(fmaxf(sred[0], sred[1]), fmaxf(sred[2], sred[3])) / 127.f + 1e-8f;
  dv = fmaxf(fmaxf(sred[4], sred[5]), fmaxf(sred[6], sred[7])) / 127.f + 1e-8f;
  dq = fmaxf(fmaxf(sred[8], sred[9]), fmaxf(sred[10], sred[11])) / 127.f + 1e-8f;
}

// R22: fake-quant q/k/v IN-PLACE, once (grid 4608). Each element read+written
// by exactly one thread (race-free). Removes the 64x-replicated qfrag work
// from attn1/attn2 staging (their VALU was 66% busy). Bit-identical values:
// same qfrag4, same exact-fmax deltas.
__global__ __launch_bounds__(256) void k_quant_kvq(unsigned short* __restrict__ qq,
                                                   unsigned short* __restrict__ kqu,
                                                   unsigned short* __restrict__ vqtu,
                                                   const float* __restrict__ wredG) {
  __shared__ float sred[12];
  float dk, dv, dq;
  redG_block(wredG, threadIdx.x, sred, dk, dv, dq);
  int bx = blockIdx.x;
  if (bx < 4096) {          // q: 8.39M elems, 8/thread
    size_t i = ((size_t)bx * 256 + threadIdx.x) * 8;
    uint4 w = *(uint4*)(qq + i);
    *(uint4*)(qq + i) = qfrag4(w, 1.f / dq, dq);
  } else if (bx < 4352) {   // k: 0.52M elems
    size_t i = ((size_t)(bx - 4096) * 256 + threadIdx.x) * 8;
    uint4 w = *(uint4*)(kqu + i);
    *(uint4*)(kqu + i) = qfrag4(w, 1.f / dk, dk);
  } else {                  // v^T: 0.52M elems
    size_t i = ((size_t)(bx - 4352) * 256 + threadIdx.x) * 8;
    uint4 w = *(uint4*)(vqtu + i);
    *(uint4*)(vqtu + i) = qfrag4(w, 1.f / dv, dv);
  }
}

// ---- 128x128-tile GEMM (proj): f32 C out, XCD-swizzled ----
__global__ __launch_bounds__(256) void k_gemm128(const unsigned short* __restrict__ Ab,
                                                 const unsigned short* __restrict__ W,
                                                 const float* __restrict__ bias,
                                                 float* __restrict__ C) {
  __shared__ unsigned short As[128 * 72];
  __shared__ unsigned short Bs[128 * 72];
  const int id = blockIdx.x;
  const int xcd = id & 7, idx = id >> 3;
  const int mt = xcd * 32 + (idx >> 1), nt = idx & 1;
  const int m0 = mt * 128, n0 = nt * 128;
  const int tid = threadIdx.x;
  const int wid = tid >> 6, lane = tid & 63;
  const int quad = lane >> 4, lr = lane & 15;
  const int wm = wid >> 1, wn = wid & 1;
  f32x4 acc[4][4] = {};
  for (int kb = 0; kb < 256; kb += 64) {
    __syncthreads();
    #pragma unroll
    for (int i = 0; i < 4; i++) {
      int c = i * 256 + tid;
      int row = c >> 3, cu = (c & 7) * 8;
      *(uint4*)&As[row * 72 + cu] = *(const uint4*)(Ab + (size_t)(m0 + row) * 256 + kb + cu);
      *(uint4*)&Bs[row * 72 + cu] = *(const uint4*)(W + (size_t)(n0 + row) * 256 + kb + cu);
    }
    __syncthreads();
    #pragma unroll
    for (int kc = 0; kc < 2; kc++) {
      bf16x8 af[4], bf[4];
      #pragma unroll
      for (int mi = 0; mi < 4; mi++)
        af[mi] = *(const bf16x8*)&As[(wm * 64 + mi * 16 + lr) * 72 + kc * 32 + quad * 8];
      #pragma unroll
      for (int ni = 0; ni < 4; ni++)
        bf[ni] = *(const bf16x8*)&Bs[(wn * 64 + ni * 16 + lr) * 72 + kc * 32 + quad * 8];
      #pragma unroll
      for (int mi = 0; mi < 4; mi++)
        #pragma unroll
        for (int ni = 0; ni < 4; ni++)
          acc[mi][ni] = __builtin_amdgcn_mfma_f32_16x16x32_bf16(af[mi], bf[ni], acc[mi][ni], 0, 0, 0);
    }
  }
  #pragma unroll
  for (int mi = 0; mi < 4; mi++)
    #pragma unroll
    for (int ni = 0; ni < 4; ni++) {
      int col = n0 + wn * 64 + ni * 16 + lr;
      float bv = bias[col];
      #pragma unroll
      for (int r = 0; r < 4; r++) {
        int row = m0 + wm * 64 + mi * 16 + quad * 4 + r;
        C[(size_t)row * 256 + col] = acc[mi][ni][r] + bv;
      }
    }
}

// ---- conv GEMM: 2048x256xK4096, split-K=4, im2col fused (bf16 x); flat grid 512
__global__ __launch_bounds__(256) void k_conv_sk(const unsigned short* __restrict__ xb,
                                                 const unsigned short* __restrict__ W,
                                                 float* __restrict__ C) {
  __shared__ unsigned short As[64 * 136];
  __shared__ unsigned short Bs[64 * 136];
  const int id = blockIdx.x;
  const int xcd = id & 7, idx = id >> 3;
  const int a = idx >> 2, nt = idx & 3;
  const int ag = xcd * 16 + a;
  const int mt = ag & 31, z = ag >> 5;
  const int m0 = mt * 64, n0 = nt * 64;
  const int kOff = z * 1024;
  C += (size_t)z * 2048 * 256;
  const int tid = threadIdx.x;
  const int wid = tid >> 6, lane = tid & 63;
  const int quad = lane >> 4, lr = lane & 15;
  const int wm = wid >> 1, wn = wid & 1;
  f32x4 acc[2][2] = {};
  for (int kb = 0; kb < 1024; kb += 128) {
    __syncthreads();
    #pragma unroll
    for (int i = 0; i < 4; i++) {
      int c = i * 256 + tid;
      int row = c >> 4, cu = (c & 15) * 8;
      int kk = kOff + kb + cu;
      int m = m0 + row;
      int b = m >> 8, p = m & 255, ph = p >> 4, pw = p & 15;
      int q = kk >> 8, ii = kk & 255;
      int n = (ph * 4 + (q >> 2)) * 64 + pw * 4 + (q & 3);
      *(uint4*)&As[row * 136 + cu] = *(const uint4*)(xb + ((size_t)(b * 4096 + n) * 256 + ii));
      *(uint4*)&Bs[row * 136 + cu] = *(const uint4*)(W + (size_t)(n0 + row) * 4096 + kk);
    }
    __syncthreads();
    #pragma unroll
    for (int kc = 0; kc < 4; kc++) {
      bf16x8 af0 = *(const bf16x8*)&As[(wm * 32 + lr) * 136 + kc * 32 + quad * 8];
      bf16x8 af1 = *(const bf16x8*)&As[(wm * 32 + 16 + lr) * 136 + kc * 32 + quad * 8];
      bf16x8 bf0 = *(const bf16x8*)&Bs[(wn * 32 + lr) * 136 + kc * 32 + quad * 8];
      bf16x8 bf1 = *(const bf16x8*)&Bs[(wn * 32 + 16 + lr) * 136 + kc * 32 + quad * 8];
      acc[0][0] = __builtin_amdgcn_mfma_f32_16x16x32_bf16(af0, bf0, acc[0][0], 0, 0, 0);
      acc[0][1] = __builtin_amdgcn_mfma_f32_16x16x32_bf16(af0, bf1, acc[0][1], 0, 0, 0);
      acc[1][0] = __builtin_amdgcn_mfma_f32_16x16x32_bf16(af1, bf0, acc[1][0], 0, 0, 0);
      acc[1][1] = __builtin_amdgcn_mfma_f32_16x16x32_bf16(af1, bf1, acc[1][1], 0, 0, 0);
    }
  }
  #pragma unroll
  for (int mi = 0; mi < 2; mi++)
    #pragma unroll
    for (int ni = 0; ni < 2; ni++) {
      int col = n0 + wn * 32 + ni * 16 + lr;
      #pragma unroll
      for (int r = 0; r < 4; r++) {
        int row = m0 + wm * 32 + mi * 16 + quad * 4 + r;
        C[(size_t)row * 256 + col] = acc[mi][ni][r];
      }
    }
}

// LayerNorm over C=256; sums 4 split-K conv partials + sr_b first
__global__ __launch_bounds__(256) void k_ln(const float* __restrict__ convp, const float* srb,
                                            const float* g, const float* bb,
                                            unsigned short* __restrict__ xn) {
  int row = blockIdx.x, c = threadIdx.x;
  float v = srb[c];
  #pragma unroll
  for (int s = 0; s < 4; s++) v += convp[s * 524288 + row * 256 + c];
  __shared__ float red[4];
  float s = v;
  #pragma unroll
  for (int d = 1; d < 64; d <<= 1) s += __shfl_xor(s, d, 64);
  if ((c & 63) == 0) red[c >> 6] = s;
  __syncthreads();
  float mu = (red[0] + red[1] + red[2] + red[3]) * (1.f / 256.f);
  __syncthreads();
  float dv = v - mu;
  float s2 = dv * dv;
  #pragma unroll
  for (int d = 1; d < 64; d <<= 1) s2 += __shfl_xor(s2, d, 64);
  if ((c & 63) == 0) red[c >> 6] = s2;
  __syncthreads();
  float var = (red[0] + red[1] + red[2] + red[3]) * (1.f / 256.f);
  float rs = 1.f / sqrtf(var + 1e-5f);
  xn[row * 256 + c] = f2bf(dv * rs * g[c] + bb[c]);
}

// attention pass 1 (R22): q/k pre-quantized by k_quant_kvq => staging is a
// plain copy, q a direct load; no prologue reductions. Swapped QK^T; per-block
// (wmin,wmax) -> pstat (no atomics). Grid 32x64.
__global__ __launch_bounds__(256) void k_attn1(const unsigned short* __restrict__ qq,
                                               const unsigned short* __restrict__ kqu,
                                               float2* __restrict__ rowstats,
                                               float2* __restrict__ pstat) {
  __shared__ unsigned short KsL[8192];  // 16 KB: [t(16)][lane(64)] x 8 shorts
  __shared__ float red[8];
  const int bh = blockIdx.y;
  const int row0 = blockIdx.x * 128;
  const int tid = threadIdx.x, wid = tid >> 6, lane = tid & 63, quad = lane >> 4, lr = lane & 15;
  const float c2 = 0.17677669529663687f * 1.4426950408889634f;  // 32^-0.5 * log2(e)
  const unsigned short* kb = kqu + (size_t)bh * 8192;
  #pragma unroll
  for (int k = 0; k < 4; k++) {
    int cid = k * 256 + tid;                 // 1024 chunks of 16B
    int seg = cid >> 6, lc = cid & 63, qc = lc >> 4, lrc = lc & 15;
    *(uint4*)&KsL[cid * 8] = *(const uint4*)(kb + (seg * 16 + lrc) * 32 + qc * 8);
  }
  __syncthreads();
  float wmin = 1e30f, wmax = 0.f;
  #pragma unroll
  for (int g = 0; g < 2; g++) {
    int rowg = row0 + g * 64 + wid * 16 + lr;
    bf16x8 qf = *(const bf16x8*)(qq + ((size_t)bh * 4096 + rowg) * 32 + quad * 8);
    f32x4 acc[16] = {};
    #pragma unroll
    for (int t = 0; t < 16; t++) {
      bf16x8 kf = *(const bf16x8*)&KsL[(t * 64 + quad * 16 + lr) * 8];
      acc[t] = __builtin_amdgcn_mfma_f32_16x16x32_bf16(kf, qf, acc[t], 0, 0, 0);
    }
    float mxr = -1e30f, mnr = 1e30f;
    #pragma unroll
    for (int t = 0; t < 16; t++)
      #pragma unroll
      for (int r = 0; r < 4; r++) {
        float s = acc[t][r];
        mxr = fmaxf(mxr, s); mnr = fminf(mnr, s);
      }
    #pragma unroll
    for (int d = 16; d < 64; d <<= 1) {
      mxr = fmaxf(mxr, __shfl_xor(mxr, d, 64));
      mnr = fminf(mnr, __shfl_xor(mnr, d, 64));
    }
    float m2 = mxr * c2;
    float l = 0.f;
    #pragma unroll
    for (int t = 0; t < 16; t++)
      #pragma unroll
      for (int r = 0; r < 4; r++)
        l += exp2_(fmaf(acc[t][r], c2, -m2));
    #pragma unroll
    for (int d = 16; d < 64; d <<= 1) l += __shfl_xor(l, d, 64);
    float inv_l = 1.f / l;
    if (lane < 16)
      rowstats[(size_t)bh * 4096 + rowg] = make_float2(m2, inv_l);
    wmax = fmaxf(wmax, inv_l);
    wmin = fminf(wmin, exp2_((mnr - mxr) * c2) * inv_l);
  }
  #pragma unroll
  for (int d = 1; d < 16; d <<= 1) {
    wmax = fmaxf(wmax, __shfl_xor(wmax, d, 64));
    wmin = fminf(wmin, __shfl_xor(wmin, d, 64));
  }
  if (lane == 0) { red[wid] = wmin; red[4 + wid] = wmax; }
  __syncthreads();
  if (tid == 0) {
    float mn = fminf(fminf(red[0], red[1]), fminf(red[2], red[3]));
    float mx = fmaxf(fmaxf(red[4], red[5]), fmaxf(red[6], red[7]));
    pstat[blockIdx.y * 32 + blockIdx.x] = make_float2(mn, mx);
  }
}

// attention pass 2 (R22): q/k/v pre-quantized => staging is a plain copy;
// prologue reduces pstat only. Swapped-QK in-register softmax/quant.
__global__ __launch_bounds__(256) void k_attn2(const unsigned short* __restrict__ qq,
                                               const unsigned short* __restrict__ kqu,
                                               const unsigned short* __restrict__ vqtu,
                                               const float2* __restrict__ pstat,
                                               const float2* __restrict__ rowstats,
                                               unsigned short* __restrict__ attn_out) {
  __shared__ unsigned short KsL[8192];  // 16 KB: [t(16)][lane(64)] chunks
  __shared__ unsigned short VsL[8192];  // 16 KB: [ks*2+half(16)][lane(64)] chunks
  __shared__ float red[8];
  const int bh = blockIdx.y, b = bh >> 3, h = bh & 7;
  const int row0 = blockIdx.x * 128;
  const int tid = threadIdx.x, wid = tid >> 6, lane = tid & 63, quad = lane >> 4, lr = lane & 15;
  const float c2 = 0.17677669529663687f * 1.4426950408889634f;
  const unsigned short* kb = kqu + (size_t)bh * 8192;
  const unsigned short* vb = vqtu + (size_t)bh * 8192;
  // prologue: reduce pstat[2048] -> pmin, pmax (exact => identical across blocks)
  {
    float mn = 1e30f, mx = 0.f;
    #pragma unroll
    for (int i = 0; i < 8; i++) {
      float2 v = pstat[tid + i * 256];
      mn = fminf(mn, v.x); mx = fmaxf(mx, v.y);
    }
    #pragma unroll
    for (int d = 1; d < 64; d <<= 1) {
      mn = fminf(mn, __shfl_xor(mn, d, 64));
      mx = fmaxf(mx, __shfl_xor(mx, d, 64));
    }
    if (lane == 0) { red[wid] = mn; red[4 + wid] = mx; }
  }
  #pragma unroll
  for (int k = 0; k < 4; k++) {
    int cid = k * 256 + tid;
    int seg = cid >> 6, lc = cid & 63, qc = lc >> 4, lrc = lc & 15;
    *(uint4*)&KsL[cid * 8] = *(const uint4*)(kb + (seg * 16 + lrc) * 32 + qc * 8);
    *(uint4*)&VsL[cid * 8] = *(const uint4*)(vb + ((seg & 1) * 16 + lrc) * 256 + (seg >> 1) * 32 + qc * 8);
  }
  __syncthreads();
  float pmin = fminf(fminf(red[0], red[1]), fminf(red[2], red[3]));
  float pmax = fmaxf(fmaxf(red[4], red[5]), fmaxf(red[6], red[7]));
  float delta = (pmax - pmin) / 255.f + 1e-8f;
  float zp = rintf(-pmin / delta);
  float qlo = -zp, qhi = 255.f - zp;
  #pragma unroll
  for (int g = 0; g < 2; g++) {
    int rowg = row0 + g * 64 + wid * 16 + lr;
    bf16x8 qf = *(const bf16x8*)(qq + ((size_t)bh * 4096 + rowg) * 32 + quad * 8);
    float2 st = rowstats[(size_t)bh * 4096 + rowg];
    f32x4 acc[16] = {};
    #pragma unroll
    for (int t = 0; t < 16; t++) {
      bf16x8 kf = *(const bf16x8*)&KsL[(t * 64 + quad * 16 + lr) * 8];
      acc[t] = __builtin_amdgcn_mfma_f32_16x16x32_bf16(kf, qf, acc[t], 0, 0, 0);
    }
    // p*inv_delta = exp2(s*c2 - m2 + log2(inv_l/delta)); out = clamp(rint(.),qlo,qhi)*delta
    float ofs = __log2f(st.y / delta) - st.x;
    f32x4 o0 = {}, o1 = {};
    #pragma unroll
    for (int ks = 0; ks < 8; ks++) {
      float pv[8];
      #pragma unroll
      for (int half = 0; half < 2; half++) {
        #pragma unroll
        for (int r = 0; r < 4; r++) {
          float v = exp2_(fmaf(acc[2 * ks + half][r], c2, ofs));
          pv[half * 4 + r] = fminf(fmaxf(rintf(v), qlo), qhi) * delta;
        }
      }
      unsigned wa = cvtpk(pv[0], pv[1]);
      unsigned wb = cvtpk(pv[2], pv[3]);
      unsigned wc = cvtpk(pv[4], pv[5]);
      unsigned wd = cvtpk(pv[6], pv[7]);
      pl32swap(wa, wc);
      pl16swap(wa, wc);
      pl32swap(wb, wd);
      pl16swap(wb, wd);
      uint4 w = make_uint4(wa, wb, wc, wd);
      bf16x8 pa = *(bf16x8*)&w;
      bf16x8 b0 = *(const bf16x8*)&VsL[((ks * 2 + 0) * 64 + quad * 16 + lr) * 8];
      bf16x8 b1 = *(const bf16x8*)&VsL[((ks * 2 + 1) * 64 + quad * 16 + lr) * 8];
      o0 = __builtin_amdgcn_mfma_f32_16x16x32_bf16(pa, b0, o0, 0, 0, 0);
      o1 = __builtin_amdgcn_mfma_f32_16x16x32_bf16(pa, b1, o1, 0, 0, 0);
    }
    #pragma unroll
    for (int r = 0; r < 4; r++) {
      int n = row0 + g * 64 + wid * 16 + quad * 4 + r;
      size_t base = ((size_t)(b * 4096) + n) * 256 + h * 32;
      attn_out[base + lr] = f2bf(o0[r]);
      attn_out[base + 16 + lr] = f2bf(o1[r]);
    }
  }
}

extern "C" void kernel_launch(void* const* d_in, const int* in_sizes, int n_in,
                              void* d_out, int out_size, void* d_ws, size_t ws_size,
                              hipStream_t stream) {
  const float* x      = (const float*)d_in[0];
  const float* q_w    = (const float*)d_in[1];
  const float* q_b    = (const float*)d_in[2];
  const float* kv_w   = (const float*)d_in[3];
  const float* kv_b   = (const float*)d_in[4];
  const float* sr_w   = (const float*)d_in[5];
  const float* sr_b   = (const float*)d_in[6];
  const float* norm_g = (const float*)d_in[7];
  const float* norm_b = (const float*)d_in[8];
  const float* proj_w = (const float*)d_in[9];
  const float* proj_b = (const float*)d_in[10];
  float* out = (float*)d_out;

  char* ws = (char*)d_ws;
  unsigned short* q_wq    = (unsigned short*)(ws + 256);       // 128 KB
  unsigned short* kv_wq   = (unsigned short*)(ws + 131328);    // 256 KB
  unsigned short* proj_wq = (unsigned short*)(ws + 393472);    // 128 KB
  unsigned short* sr_wq   = (unsigned short*)(ws + 524544);    // 2 MB   -> 2621696
  unsigned short* xn      = (unsigned short*)(ws + 2621696);   // 1 MB   -> 3670272
  unsigned short* kqu     = (unsigned short*)(ws + 7864576);   // 1 MB (bf16 k)
  unsigned short* vqtu    = (unsigned short*)(ws + 8913152);   // 1 MB (bf16 v^T)
  float2*         rowstats= (float2*)(ws + 9961728);           // 2 MB   -> 12058880
  float*          convp   = (float*)(ws + 12058880);           // 8 MB (4 partials)
  unsigned short* attn_o  = (unsigned short*)(ws + 12058880);  // over convp (dead after k_ln); 16 MB
  float2*         pstat   = (float2*)(ws + 28836096);          // 16 KB
  unsigned short* qq      = (unsigned short*)(ws + 45613312);  // 16 MB (bf16 q)
  unsigned short* xb      = (unsigned short*)(ws + 62390528);  // 16 MB (x as bf16) -> 79167744
  float*          wredW   = (float*)(ws + 79167744);           // 1 KB (absmax partials)
  float*          wredG   = (float*)(ws + 79168768);           // 12 KB (gemm amax partials)

  k_absmax4<<<dim3(64, 4), 256, 0, stream>>>(q_w, kv_w, sr_w, proj_w, wredW);
  // weight quant + x->bf16 cast (reduces wredW in-prologue)
  k_quantw<<<4096, 256, 0, stream>>>(q_w, kv_w, proj_w, sr_w, x,
                                     q_wq, kv_wq, proj_wq, sr_wq, xb, wredW);
  // conv GEMM (im2col fused, split-K=4, XCD-swizzled): 2048x256x4096
  k_conv_sk<<<512, 256, 0, stream>>>(xb, sr_wq, convp);
  k_ln<<<2048, 256, 0, stream>>>(convp, sr_b, norm_g, norm_b, xn);
  // FUSED kv-GEMM (256 blocks) + q-GEMM (512 blocks); per-wave amax -> wredG
  k_gemm_qkv<<<768, 256, 0, stream>>>(xn, kv_wq, kv_b, xb, q_wq, q_b,
                                      kqu, vqtu, qq, wredG);
  // in-place fake-quant of q/k/v (reduces wredG in-prologue)
  k_quant_kvq<<<4608, 256, 0, stream>>>(qq, kqu, vqtu, wredG);
  // attn1: plain staging, direct q loads
  k_attn1<<<dim3(32, 64), 256, 0, stream>>>(qq, kqu, rowstats, pstat);
  // attn2: plain staging, pstat reduce in-prologue
  k_attn2<<<dim3(32, 64), 256, 0, stream>>>(qq, kqu, vqtu, pstat, rowstats, attn_o);
  // proj GEMM: 32768x256x256, 128-tile, XCD-swizzled
  k_gemm128<<<512, 256, 0, stream>>>(attn_o, proj_wq, proj_b, out);
}

// Round 15
// 225.997 us; speedup vs baseline: 1.0480x; 1.0395x over previous
//
#include <hip/hip_runtime.h>
#include <stdint.h>

typedef float f32x4 __attribute__((ext_vector_type(4)));
typedef __bf16 bf16x8 __attribute__((ext_vector_type(8)));

#define DEV __device__ __forceinline__

DEV unsigned short f2bf(float f) {
  unsigned u = __float_as_uint(f);
  u += 0x7FFFu + ((u >> 16) & 1u);   // round-to-nearest-even
  return (unsigned short)(u >> 16);
}

DEV float exp2_(float x) {
#if __has_builtin(__builtin_amdgcn_exp2f)
  return __builtin_amdgcn_exp2f(x);   // raw v_exp_f32; args in [-60,0] => normal range
#else
  return exp2f(x);
#endif
}

// pack two f32 -> one u32 of 2 bf16 (RNE), single instruction
DEV unsigned cvtpk(float lo, float hi) {
  unsigned r;
  asm("v_cvt_pk_bf16_f32 %0, %1, %2" : "=v"(r) : "v"(lo), "v"(hi));
  return r;
}

// a' = {a.lo32, b.lo32}; b' = {a.hi32, b.hi32}
DEV void pl32swap(unsigned &a, unsigned &b) {
#if __has_builtin(__builtin_amdgcn_permlane32_swap)
  auto r = __builtin_amdgcn_permlane32_swap(a, b, false, false);
  a = r[0]; b = r[1];
#else
  asm("v_permlane32_swap_b32 %0, %1" : "+v"(a), "+v"(b));
#endif
}

// rows = 16-lane groups: a' = {a.r0, b.r0, a.r2, b.r2}; b' = {a.r1, b.r1, a.r3, b.r3}
DEV void pl16swap(unsigned &a, unsigned &b) {
#if __has_builtin(__builtin_amdgcn_permlane16_swap)
  auto r = __builtin_amdgcn_permlane16_swap(a, b, false, false);
  a = r[0]; b = r[1];
#else
  asm("v_permlane16_swap_b32 %0, %1" : "+v"(a), "+v"(b));
#endif
}

// symmetric fake-quant of 8 packed bf16 in-register (deterministic: every
// consumer of the same bytes + same delta produces IDENTICAL results).
DEV uint4 qfrag4(uint4 w, float idq, float dq) {
  unsigned o[4];
  const unsigned* wi = &w.x;
  #pragma unroll
  for (int i = 0; i < 4; i++) {
    float lo = __uint_as_float(wi[i] << 16);
    float hi = __uint_as_float(wi[i] & 0xffff0000u);
    lo = fminf(fmaxf(rintf(lo * idq), -128.f), 127.f) * dq;
    hi = fminf(fmaxf(rintf(hi * idq), -128.f), 127.f) * dq;
    o[i] = cvtpk(lo, hi);
  }
  return make_uint4(o[0], o[1], o[2], o[3]);
}

// per-weight absmax partials: plain stores (NO same-line atomics; R15-R17).
// Block (bx, t) writes wred[t*64 + bx]; consumers re-reduce (cross-dispatch
// visibility is guaranteed at kernel boundaries).
__global__ __launch_bounds__(256) void k_absmax4(const float* w0, const float* w1,
                                                 const float* w2, const float* w3,
                                                 float* wred) {
  const float* srcs[4] = {w0, w1, w2, w3};
  const int ns[4] = {65536, 131072, 1048576, 65536};
  int t = blockIdx.y;
  const float* src = srcs[t];
  int n = ns[t];
  float m = 0.f;
  for (int i = blockIdx.x * 256 + threadIdx.x; i < n; i += gridDim.x * 256)
    m = fmaxf(m, fabsf(src[i]));
  #pragma unroll
  for (int d = 1; d < 64; d <<= 1) m = fmaxf(m, __shfl_xor(m, d, 64));
  __shared__ float red[4];
  if ((threadIdx.x & 63) == 0) red[threadIdx.x >> 6] = m;
  __syncthreads();
  if (threadIdx.x == 0) {
    m = fmaxf(fmaxf(red[0], red[1]), fmaxf(red[2], red[3]));
    wred[t * 64 + blockIdx.x] = m;
  }
}

// fused weight quant + x->bf16 cast (grid.x = 4096); reduces wred[4][64]
// in-prologue (fmax is exact => bit-identical across blocks).
__global__ __launch_bounds__(256) void k_quantw(const float* qw, const float* kvw,
                                                const float* prw, const float* srw,
                                                const float* xf,
                                                unsigned short* qo, unsigned short* kvo,
                                                unsigned short* pro, unsigned short* sro,
                                                unsigned short* xbo,
                                                const float* __restrict__ wred) {
  __shared__ float sred[4];
  {
    float v = wred[threadIdx.x];          // 256 = 4 weights x 64 partials
    #pragma unroll
    for (int d = 1; d < 64; d <<= 1) v = fmaxf(v, __shfl_xor(v, d, 64));
    if ((threadIdx.x & 63) == 0) sred[threadIdx.x >> 6] = v;
    __syncthreads();
  }
  float d_q  = sred[0] / 127.f + 1e-8f;
  float d_kv = sred[1] / 127.f + 1e-8f;
  float d_sr = sred[2] / 127.f + 1e-8f;
  float d_pr = sred[3] / 127.f + 1e-8f;
  int bx = blockIdx.x;
  int tid = bx * 256 + threadIdx.x;
  {
    int oo = tid >> 12;
    int rem = tid & 4095;
    int khkw = rem >> 8;
    int i = rem & 255;
    float x = srw[oo * 4096 + i * 16 + khkw];
    sro[tid] = f2bf(fminf(fmaxf(rintf(x / d_sr), -128.f), 127.f) * d_sr);
  }
  {
    // x cast: 8 contiguous f32 -> 8 bf16 per thread
    const float4* xs = (const float4*)(xf + (size_t)tid * 8);
    float4 v0 = xs[0], v1 = xs[1];
    unsigned w0 = ((unsigned)f2bf(v0.y) << 16) | f2bf(v0.x);
    unsigned w1 = ((unsigned)f2bf(v0.w) << 16) | f2bf(v0.z);
    unsigned w2 = ((unsigned)f2bf(v1.y) << 16) | f2bf(v1.x);
    unsigned w3 = ((unsigned)f2bf(v1.w) << 16) | f2bf(v1.z);
    *(uint4*)(xbo + (size_t)tid * 8) = make_uint4(w0, w1, w2, w3);
  }
  if (bx < 512) {
    kvo[tid] = f2bf(fminf(fmaxf(rintf(kvw[tid] / d_kv), -128.f), 127.f) * d_kv);
  }
  if (bx < 256) {
    qo[tid] = f2bf(fminf(fmaxf(rintf(qw[tid] / d_q), -128.f), 127.f) * d_q);
    pro[tid] = f2bf(fminf(fmaxf(rintf(prw[tid] / d_pr), -128.f), 127.f) * d_pr);
  }
}

// ---- FUSED kv-GEMM + q-GEMM, one dispatch (768 blocks) ----
// Per-wave amax -> wredG[bid*4+wid] (plain stores; NO same-line atomics).
__global__ __launch_bounds__(256) void k_gemm_qkv(const unsigned short* __restrict__ xnrm,
                                                  const unsigned short* __restrict__ kvw,
                                                  const float* __restrict__ kvb,
                                                  const unsigned short* __restrict__ xb,
                                                  const unsigned short* __restrict__ qw,
                                                  const float* __restrict__ qb,
                                                  unsigned short* __restrict__ kqu,
                                                  unsigned short* __restrict__ vqtu,
                                                  unsigned short* __restrict__ qq,
                                                  float* __restrict__ wredG) {
  __shared__ unsigned short smem[18432];  // 36.9 KB union
  const int tid = threadIdx.x;
  const int wid = tid >> 6, lane = tid & 63;
  const int quad = lane >> 4, lr = lane & 15;
  const int wm = wid >> 1, wn = wid & 1;
  if (blockIdx.x < 256) {
    // ---------------- kv GEMM ----------------
    unsigned short* As = smem;            // 64*136
    unsigned short* Bs = smem + 8704;     // 64*136
    const int n0 = (blockIdx.x & 7) * 64, m0 = (blockIdx.x >> 3) * 64;
    f32x4 acc[2][2] = {};
    for (int kb = 0; kb < 256; kb += 128) {
      __syncthreads();
      #pragma unroll
      for (int i = 0; i < 4; i++) {
        int c = i * 256 + tid;
        int row = c >> 4, cu = (c & 15) * 8;
        *(uint4*)&As[row * 136 + cu] = *(const uint4*)(xnrm + (size_t)(m0 + row) * 256 + kb + cu);
        *(uint4*)&Bs[row * 136 + cu] = *(const uint4*)(kvw + (size_t)(n0 + row) * 256 + kb + cu);
      }
      __syncthreads();
      #pragma unroll
      for (int kc = 0; kc < 4; kc++) {
        bf16x8 af0 = *(const bf16x8*)&As[(wm * 32 + lr) * 136 + kc * 32 + quad * 8];
        bf16x8 af1 = *(const bf16x8*)&As[(wm * 32 + 16 + lr) * 136 + kc * 32 + quad * 8];
        bf16x8 bf0 = *(const bf16x8*)&Bs[(wn * 32 + lr) * 136 + kc * 32 + quad * 8];
        bf16x8 bf1 = *(const bf16x8*)&Bs[(wn * 32 + 16 + lr) * 136 + kc * 32 + quad * 8];
        acc[0][0] = __builtin_amdgcn_mfma_f32_16x16x32_bf16(af0, bf0, acc[0][0], 0, 0, 0);
        acc[0][1] = __builtin_amdgcn_mfma_f32_16x16x32_bf16(af0, bf1, acc[0][1], 0, 0, 0);
        acc[1][0] = __builtin_amdgcn_mfma_f32_16x16x32_bf16(af1, bf0, acc[1][0], 0, 0, 0);
        acc[1][1] = __builtin_amdgcn_mfma_f32_16x16x32_bf16(af1, bf1, acc[1][1], 0, 0, 0);
      }
    }
    float amax = 0.f;
    #pragma unroll
    for (int mi = 0; mi < 2; mi++)
      #pragma unroll
      for (int ni = 0; ni < 2; ni++) {
        int col = n0 + wn * 32 + ni * 16 + lr;
        float bv = kvb[col];
        #pragma unroll
        for (int r = 0; r < 4; r++) {
          int row = m0 + wm * 32 + mi * 16 + quad * 4 + r;
          float v = acc[mi][ni][r] + bv;
          int b = row >> 8, n2 = row & 255;
          int h = (col >> 5) & 7, j = col & 31;
          if (col < 256)
            kqu[((size_t)((b * 8 + h) * 256 + n2)) * 32 + j] = f2bf(v);
          else
            vqtu[((size_t)((b * 8 + h) * 32 + j)) * 256 + n2] = f2bf(v);
          amax = fmaxf(amax, fabsf(v));
        }
      }
    #pragma unroll
    for (int d = 1; d < 64; d <<= 1) amax = fmaxf(amax, __shfl_xor(amax, d, 64));
    if (lane == 0) wredG[(blockIdx.x << 2) | wid] = amax;
  } else {
    // ---------------- q GEMM (XCD-swizzled 128x128) ----------------
    unsigned short* As = smem;            // 128*72
    unsigned short* Bs = smem + 9216;     // 128*72
    const int id = blockIdx.x - 256;
    const int xcd = id & 7, idx = id >> 3;          // 64 blocks per XCD
    const int mt = xcd * 32 + (idx >> 1), nt = idx & 1;
    const int m0 = mt * 128, n0 = nt * 128;
    f32x4 acc[4][4] = {};
    for (int kb = 0; kb < 256; kb += 64) {
      __syncthreads();
      #pragma unroll
      for (int i = 0; i < 4; i++) {
        int c = i * 256 + tid;
        int row = c >> 3, cu = (c & 7) * 8;
        *(uint4*)&As[row * 72 + cu] = *(const uint4*)(xb + (size_t)(m0 + row) * 256 + kb + cu);
        *(uint4*)&Bs[row * 72 + cu] = *(const uint4*)(qw + (size_t)(n0 + row) * 256 + kb + cu);
      }
      __syncthreads();
      #pragma unroll
      for (int kc = 0; kc < 2; kc++) {
        bf16x8 af[4], bf[4];
        #pragma unroll
        for (int mi = 0; mi < 4; mi++)
          af[mi] = *(const bf16x8*)&As[(wm * 64 + mi * 16 + lr) * 72 + kc * 32 + quad * 8];
        #pragma unroll
        for (int ni = 0; ni < 4; ni++)
          bf[ni] = *(const bf16x8*)&Bs[(wn * 64 + ni * 16 + lr) * 72 + kc * 32 + quad * 8];
        #pragma unroll
        for (int mi = 0; mi < 4; mi++)
          #pragma unroll
          for (int ni = 0; ni < 4; ni++)
            acc[mi][ni] = __builtin_amdgcn_mfma_f32_16x16x32_bf16(af[mi], bf[ni], acc[mi][ni], 0, 0, 0);
      }
    }
    float amax = 0.f;
    #pragma unroll
    for (int mi = 0; mi < 4; mi++)
      #pragma unroll
      for (int ni = 0; ni < 4; ni++) {
        int col = n0 + wn * 64 + ni * 16 + lr;
        float bv = qb[col];
        #pragma unroll
        for (int r = 0; r < 4; r++) {
          int row = m0 + wm * 64 + mi * 16 + quad * 4 + r;
          float v = acc[mi][ni][r] + bv;
          int b = row >> 12, nn = row & 4095;
          int h = col >> 5, j = col & 31;
          qq[((size_t)(b * 8 + h) * 4096 + nn) * 32 + j] = f2bf(v);
          amax = fmaxf(amax, fabsf(v));
        }
      }
    #pragma unroll
    for (int d = 1; d < 64; d <<= 1) amax = fmaxf(amax, __shfl_xor(amax, d, 64));
    if (lane == 0) wredG[(blockIdx.x << 2) | wid] = amax;
  }
}

// per-block wredG[3072] reduction (exact fmax => order-independent, identical
// across all consumer blocks): dk=kmax/127, dv=vmax/127, dq=qmax/127.
DEV void redG_block(const float* __restrict__ wredG, int tid, float* sred,
                    float& dk, float& dv, float& dq) {
  int wid = tid >> 6, lane = tid & 63;
  float mk = 0.f, mv = 0.f, mq = 0.f;
  #pragma unroll
  for (int i = 0; i < 12; i++) {
    int idx = tid + i * 256;
    float v = wredG[idx];
    int bid = idx >> 2;
    if (bid < 256) {
      if ((bid & 7) < 4) mk = fmaxf(mk, v);
      else               mv = fmaxf(mv, v);
    } else {
      mq = fmaxf(mq, v);
    }
  }
  #pragma unroll
  for (int d = 1; d < 64; d <<= 1) {
    mk = fmaxf(mk, __shfl_xor(mk, d, 64));
    mv = fmaxf(mv, __shfl_xor(mv, d, 64));
    mq = fmaxf(mq, __shfl_xor(mq, d, 64));
  }
  if (lane == 0) { sred[wid] = mk; sred[4 + wid] = mv; sred[8 + wid] = mq; }
  __syncthreads();
  dk = fmaxf(fmaxf(sred[0], sred[1]), fmaxf(sred[2], sred[3])) / 127.f + 1e-8f;
  dv = fmaxf(fmaxf(sred[4], sred[5]), fmaxf(sred[6], sred[7])) / 127.f + 1e-8f;
  dq = fmaxf(fmaxf(sred[8], sred[9]), fmaxf(sred[10], sred[11])) / 127.f + 1e-8f;
}

// fake-quant q/k/v IN-PLACE, once (grid 4608). Each element read+written by
// exactly one thread (race-free). Bit-identical values everywhere.
__global__ __launch_bounds__(256) void k_quant_kvq(unsigned short* __restrict__ qq,
                                                   unsigned short* __restrict__ kqu,
                                                   unsigned short* __restrict__ vqtu,
                                                   const float* __restrict__ wredG) {
  __shared__ float sred[12];
  float dk, dv, dq;
  redG_block(wredG, threadIdx.x, sred, dk, dv, dq);
  int bx = blockIdx.x;
  if (bx < 4096) {          // q: 8.39M elems, 8/thread
    size_t i = ((size_t)bx * 256 + threadIdx.x) * 8;
    uint4 w = *(uint4*)(qq + i);
    *(uint4*)(qq + i) = qfrag4(w, 1.f / dq, dq);
  } else if (bx < 4352) {   // k: 0.52M elems
    size_t i = ((size_t)(bx - 4096) * 256 + threadIdx.x) * 8;
    uint4 w = *(uint4*)(kqu + i);
    *(uint4*)(kqu + i) = qfrag4(w, 1.f / dk, dk);
  } else {                  // v^T: 0.52M elems
    size_t i = ((size_t)(bx - 4352) * 256 + threadIdx.x) * 8;
    uint4 w = *(uint4*)(vqtu + i);
    *(uint4*)(vqtu + i) = qfrag4(w, 1.f / dv, dv);
  }
}

// ---- 128x128-tile GEMM (proj): f32 C out, XCD-swizzled ----
__global__ __launch_bounds__(256) void k_gemm128(const unsigned short* __restrict__ Ab,
                                                 const unsigned short* __restrict__ W,
                                                 const float* __restrict__ bias,
                                                 float* __restrict__ C) {
  __shared__ unsigned short As[128 * 72];
  __shared__ unsigned short Bs[128 * 72];
  const int id = blockIdx.x;
  const int xcd = id & 7, idx = id >> 3;
  const int mt = xcd * 32 + (idx >> 1), nt = idx & 1;
  const int m0 = mt * 128, n0 = nt * 128;
  const int tid = threadIdx.x;
  const int wid = tid >> 6, lane = tid & 63;
  const int quad = lane >> 4, lr = lane & 15;
  const int wm = wid >> 1, wn = wid & 1;
  f32x4 acc[4][4] = {};
  for (int kb = 0; kb < 256; kb += 64) {
    __syncthreads();
    #pragma unroll
    for (int i = 0; i < 4; i++) {
      int c = i * 256 + tid;
      int row = c >> 3, cu = (c & 7) * 8;
      *(uint4*)&As[row * 72 + cu] = *(const uint4*)(Ab + (size_t)(m0 + row) * 256 + kb + cu);
      *(uint4*)&Bs[row * 72 + cu] = *(const uint4*)(W + (size_t)(n0 + row) * 256 + kb + cu);
    }
    __syncthreads();
    #pragma unroll
    for (int kc = 0; kc < 2; kc++) {
      bf16x8 af[4], bf[4];
      #pragma unroll
      for (int mi = 0; mi < 4; mi++)
        af[mi] = *(const bf16x8*)&As[(wm * 64 + mi * 16 + lr) * 72 + kc * 32 + quad * 8];
      #pragma unroll
      for (int ni = 0; ni < 4; ni++)
        bf[ni] = *(const bf16x8*)&Bs[(wn * 64 + ni * 16 + lr) * 72 + kc * 32 + quad * 8];
      #pragma unroll
      for (int mi = 0; mi < 4; mi++)
        #pragma unroll
        for (int ni = 0; ni < 4; ni++)
          acc[mi][ni] = __builtin_amdgcn_mfma_f32_16x16x32_bf16(af[mi], bf[ni], acc[mi][ni], 0, 0, 0);
    }
  }
  #pragma unroll
  for (int mi = 0; mi < 4; mi++)
    #pragma unroll
    for (int ni = 0; ni < 4; ni++) {
      int col = n0 + wn * 64 + ni * 16 + lr;
      float bv = bias[col];
      #pragma unroll
      for (int r = 0; r < 4; r++) {
        int row = m0 + wm * 64 + mi * 16 + quad * 4 + r;
        C[(size_t)row * 256 + col] = acc[mi][ni][r] + bv;
      }
    }
}

// ---- conv GEMM: 2048x256xK4096, split-K=4, im2col fused (bf16 x); flat grid 512
__global__ __launch_bounds__(256) void k_conv_sk(const unsigned short* __restrict__ xb,
                                                 const unsigned short* __restrict__ W,
                                                 float* __restrict__ C) {
  __shared__ unsigned short As[64 * 136];
  __shared__ unsigned short Bs[64 * 136];
  const int id = blockIdx.x;
  const int xcd = id & 7, idx = id >> 3;
  const int a = idx >> 2, nt = idx & 3;
  const int ag = xcd * 16 + a;
  const int mt = ag & 31, z = ag >> 5;
  const int m0 = mt * 64, n0 = nt * 64;
  const int kOff = z * 1024;
  C += (size_t)z * 2048 * 256;
  const int tid = threadIdx.x;
  const int wid = tid >> 6, lane = tid & 63;
  const int quad = lane >> 4, lr = lane & 15;
  const int wm = wid >> 1, wn = wid & 1;
  f32x4 acc[2][2] = {};
  for (int kb = 0; kb < 1024; kb += 128) {
    __syncthreads();
    #pragma unroll
    for (int i = 0; i < 4; i++) {
      int c = i * 256 + tid;
      int row = c >> 4, cu = (c & 15) * 8;
      int kk = kOff + kb + cu;
      int m = m0 + row;
      int b = m >> 8, p = m & 255, ph = p >> 4, pw = p & 15;
      int q = kk >> 8, ii = kk & 255;
      int n = (ph * 4 + (q >> 2)) * 64 + pw * 4 + (q & 3);
      *(uint4*)&As[row * 136 + cu] = *(const uint4*)(xb + ((size_t)(b * 4096 + n) * 256 + ii));
      *(uint4*)&Bs[row * 136 + cu] = *(const uint4*)(W + (size_t)(n0 + row) * 4096 + kk);
    }
    __syncthreads();
    #pragma unroll
    for (int kc = 0; kc < 4; kc++) {
      bf16x8 af0 = *(const bf16x8*)&As[(wm * 32 + lr) * 136 + kc * 32 + quad * 8];
      bf16x8 af1 = *(const bf16x8*)&As[(wm * 32 + 16 + lr) * 136 + kc * 32 + quad * 8];
      bf16x8 bf0 = *(const bf16x8*)&Bs[(wn * 32 + lr) * 136 + kc * 32 + quad * 8];
      bf16x8 bf1 = *(const bf16x8*)&Bs[(wn * 32 + 16 + lr) * 136 + kc * 32 + quad * 8];
      acc[0][0] = __builtin_amdgcn_mfma_f32_16x16x32_bf16(af0, bf0, acc[0][0], 0, 0, 0);
      acc[0][1] = __builtin_amdgcn_mfma_f32_16x16x32_bf16(af0, bf1, acc[0][1], 0, 0, 0);
      acc[1][0] = __builtin_amdgcn_mfma_f32_16x16x32_bf16(af1, bf0, acc[1][0], 0, 0, 0);
      acc[1][1] = __builtin_amdgcn_mfma_f32_16x16x32_bf16(af1, bf1, acc[1][1], 0, 0, 0);
    }
  }
  #pragma unroll
  for (int mi = 0; mi < 2; mi++)
    #pragma unroll
    for (int ni = 0; ni < 2; ni++) {
      int col = n0 + wn * 32 + ni * 16 + lr;
      #pragma unroll
      for (int r = 0; r < 4; r++) {
        int row = m0 + wm * 32 + mi * 16 + quad * 4 + r;
        C[(size_t)row * 256 + col] = acc[mi][ni][r];
      }
    }
}

// LayerNorm over C=256; sums 4 split-K conv partials + sr_b first
__global__ __launch_bounds__(256) void k_ln(const float* __restrict__ convp, const float* srb,
                                            const float* g, const float* bb,
                                            unsigned short* __restrict__ xn) {
  int row = blockIdx.x, c = threadIdx.x;
  float v = srb[c];
  #pragma unroll
  for (int s = 0; s < 4; s++) v += convp[s * 524288 + row * 256 + c];
  __shared__ float red[4];
  float s = v;
  #pragma unroll
  for (int d = 1; d < 64; d <<= 1) s += __shfl_xor(s, d, 64);
  if ((c & 63) == 0) red[c >> 6] = s;
  __syncthreads();
  float mu = (red[0] + red[1] + red[2] + red[3]) * (1.f / 256.f);
  __syncthreads();
  float dv = v - mu;
  float s2 = dv * dv;
  #pragma unroll
  for (int d = 1; d < 64; d <<= 1) s2 += __shfl_xor(s2, d, 64);
  if ((c & 63) == 0) red[c >> 6] = s2;
  __syncthreads();
  float var = (red[0] + red[1] + red[2] + red[3]) * (1.f / 256.f);
  float rs = 1.f / sqrtf(var + 1e-5f);
  xn[row * 256 + c] = f2bf(dv * rs * g[c] + bb[c]);
}

// attention pass 1 (R23): 512 threads (8 waves) + 33KB LDS => 4 blocks/CU x 8
// waves = 32 waves/CU (FULL occupancy; R22 measured 4 waves/SIMD + 53% stall).
// 256 rows/block. Swapped QK^T; 4-way ILP trees for the max/min chains
// (fmax/fmin exact => bit-identical). Per-block (wmin,wmax) -> pstat.
__global__ __launch_bounds__(512) void k_attn1(const unsigned short* __restrict__ qq,
                                               const unsigned short* __restrict__ kqu,
                                               float2* __restrict__ rowstats,
                                               float2* __restrict__ pstat) {
  __shared__ unsigned short KsL[8192];  // 16 KB: [t(16)][lane(64)] x 8 shorts
  __shared__ float red[16];
  const int bh = blockIdx.y;
  const int row0 = blockIdx.x * 256;
  const int tid = threadIdx.x, wid = tid >> 6, lane = tid & 63, quad = lane >> 4, lr = lane & 15;
  const float c2 = 0.17677669529663687f * 1.4426950408889634f;  // 32^-0.5 * log2(e)
  const unsigned short* kb = kqu + (size_t)bh * 8192;
  #pragma unroll
  for (int k = 0; k < 2; k++) {
    int cid = k * 512 + tid;                 // 1024 chunks of 16B
    int seg = cid >> 6, lc = cid & 63, qc = lc >> 4, lrc = lc & 15;
    *(uint4*)&KsL[cid * 8] = *(const uint4*)(kb + (seg * 16 + lrc) * 32 + qc * 8);
  }
  __syncthreads();
  float wmin = 1e30f, wmax = 0.f;
  #pragma unroll
  for (int g = 0; g < 2; g++) {
    int rowg = row0 + g * 128 + wid * 16 + lr;
    bf16x8 qf = *(const bf16x8*)(qq + ((size_t)bh * 4096 + rowg) * 32 + quad * 8);
    f32x4 acc[16] = {};
    #pragma unroll
    for (int t = 0; t < 16; t++) {
      bf16x8 kf = *(const bf16x8*)&KsL[(t * 64 + quad * 16 + lr) * 8];
      acc[t] = __builtin_amdgcn_mfma_f32_16x16x32_bf16(kf, qf, acc[t], 0, 0, 0);
    }
    // 4-way ILP accumulator trees (order-independent for fmax/fmin)
    float mx4[4] = {-1e30f, -1e30f, -1e30f, -1e30f};
    float mn4[4] = {1e30f, 1e30f, 1e30f, 1e30f};
    #pragma unroll
    for (int t = 0; t < 16; t++)
      #pragma unroll
      for (int r = 0; r < 4; r++) {
        float s = acc[t][r];
        mx4[t & 3] = fmaxf(mx4[t & 3], s);
        mn4[t & 3] = fminf(mn4[t & 3], s);
      }
    float mxr = fmaxf(fmaxf(mx4[0], mx4[1]), fmaxf(mx4[2], mx4[3]));
    float mnr = fminf(fminf(mn4[0], mn4[1]), fminf(mn4[2], mn4[3]));
    #pragma unroll
    for (int d = 16; d < 64; d <<= 1) {
      mxr = fmaxf(mxr, __shfl_xor(mxr, d, 64));
      mnr = fminf(mnr, __shfl_xor(mnr, d, 64));
    }
    float m2 = mxr * c2;
    float l = 0.f;
    #pragma unroll
    for (int t = 0; t < 16; t++)
      #pragma unroll
      for (int r = 0; r < 4; r++)
        l += exp2_(fmaf(acc[t][r], c2, -m2));
    #pragma unroll
    for (int d = 16; d < 64; d <<= 1) l += __shfl_xor(l, d, 64);
    float inv_l = 1.f / l;
    if (lane < 16)
      rowstats[(size_t)bh * 4096 + rowg] = make_float2(m2, inv_l);
    wmax = fmaxf(wmax, inv_l);
    wmin = fminf(wmin, exp2_((mnr - mxr) * c2) * inv_l);
  }
  #pragma unroll
  for (int d = 1; d < 16; d <<= 1) {
    wmax = fmaxf(wmax, __shfl_xor(wmax, d, 64));
    wmin = fminf(wmin, __shfl_xor(wmin, d, 64));
  }
  if (lane == 0) { red[wid] = wmin; red[8 + wid] = wmax; }
  __syncthreads();
  if (tid == 0) {
    float mn = 1e30f, mx = 0.f;
    #pragma unroll
    for (int w = 0; w < 8; w++) {
      mn = fminf(mn, red[w]);
      mx = fmaxf(mx, red[8 + w]);
    }
    pstat[blockIdx.y * 16 + blockIdx.x] = make_float2(mn, mx);
  }
}

// attention pass 2 (R23): 512 threads (8 waves), full 32 waves/CU occupancy;
// prologue reduces pstat[1024] only. Swapped-QK in-register softmax/quant.
__global__ __launch_bounds__(512) void k_attn2(const unsigned short* __restrict__ qq,
                                               const unsigned short* __restrict__ kqu,
                                               const unsigned short* __restrict__ vqtu,
                                               const float2* __restrict__ pstat,
                                               const float2* __restrict__ rowstats,
                                               unsigned short* __restrict__ attn_out) {
  __shared__ unsigned short KsL[8192];  // 16 KB: [t(16)][lane(64)] chunks
  __shared__ unsigned short VsL[8192];  // 16 KB: [ks*2+half(16)][lane(64)] chunks
  __shared__ float red[16];
  const int bh = blockIdx.y, b = bh >> 3, h = bh & 7;
  const int row0 = blockIdx.x * 256;
  const int tid = threadIdx.x, wid = tid >> 6, lane = tid & 63, quad = lane >> 4, lr = lane & 15;
  const float c2 = 0.17677669529663687f * 1.4426950408889634f;
  const unsigned short* kb = kqu + (size_t)bh * 8192;
  const unsigned short* vb = vqtu + (size_t)bh * 8192;
  // prologue: reduce pstat[1024] -> pmin, pmax (exact => identical across blocks)
  {
    float mn = 1e30f, mx = 0.f;
    #pragma unroll
    for (int i = 0; i < 2; i++) {
      float2 v = pstat[tid + i * 512];
      mn = fminf(mn, v.x); mx = fmaxf(mx, v.y);
    }
    #pragma unroll
    for (int d = 1; d < 64; d <<= 1) {
      mn = fminf(mn, __shfl_xor(mn, d, 64));
      mx = fmaxf(mx, __shfl_xor(mx, d, 64));
    }
    if (lane == 0) { red[wid] = mn; red[8 + wid] = mx; }
  }
  #pragma unroll
  for (int k = 0; k < 2; k++) {
    int cid = k * 512 + tid;
    int seg = cid >> 6, lc = cid & 63, qc = lc >> 4, lrc = lc & 15;
    *(uint4*)&KsL[cid * 8] = *(const uint4*)(kb + (seg * 16 + lrc) * 32 + qc * 8);
    *(uint4*)&VsL[cid * 8] = *(const uint4*)(vb + ((seg & 1) * 16 + lrc) * 256 + (seg >> 1) * 32 + qc * 8);
  }
  __syncthreads();
  float pmin = 1e30f, pmax = 0.f;
  #pragma unroll
  for (int w = 0; w < 8; w++) {
    pmin = fminf(pmin, red[w]);
    pmax = fmaxf(pmax, red[8 + w]);
  }
  float delta = (pmax - pmin) / 255.f + 1e-8f;
  float zp = rintf(-pmin / delta);
  float qlo = -zp, qhi = 255.f - zp;
  #pragma unroll
  for (int g = 0; g < 2; g++) {
    int rowg = row0 + g * 128 + wid * 16 + lr;
    bf16x8 qf = *(const bf16x8*)(qq + ((size_t)bh * 4096 + rowg) * 32 + quad * 8);
    float2 st = rowstats[(size_t)bh * 4096 + rowg];
    f32x4 acc[16] = {};
    #pragma unroll
    for (int t = 0; t < 16; t++) {
      bf16x8 kf = *(const bf16x8*)&KsL[(t * 64 + quad * 16 + lr) * 8];
      acc[t] = __builtin_amdgcn_mfma_f32_16x16x32_bf16(kf, qf, acc[t], 0, 0, 0);
    }
    // p*inv_delta = exp2(s*c2 - m2 + log2(inv_l/delta)); out = clamp(rint(.),qlo,qhi)*delta
    float ofs = __log2f(st.y / delta) - st.x;
    f32x4 o0 = {}, o1 = {};
    #pragma unroll
    for (int ks = 0; ks < 8; ks++) {
      float pv[8];
      #pragma unroll
      for (int half = 0; half < 2; half++) {
        #pragma unroll
        for (int r = 0; r < 4; r++) {
          float v = exp2_(fmaf(acc[2 * ks + half][r], c2, ofs));
          pv[half * 4 + r] = fminf(fmaxf(rintf(v), qlo), qhi) * delta;
        }
      }
      unsigned wa = cvtpk(pv[0], pv[1]);
      unsigned wb = cvtpk(pv[2], pv[3]);
      unsigned wc = cvtpk(pv[4], pv[5]);
      unsigned wd = cvtpk(pv[6], pv[7]);
      pl32swap(wa, wc);
      pl16swap(wa, wc);
      pl32swap(wb, wd);
      pl16swap(wb, wd);
      uint4 w = make_uint4(wa, wb, wc, wd);
      bf16x8 pa = *(bf16x8*)&w;
      bf16x8 b0 = *(const bf16x8*)&VsL[((ks * 2 + 0) * 64 + quad * 16 + lr) * 8];
      bf16x8 b1 = *(const bf16x8*)&VsL[((ks * 2 + 1) * 64 + quad * 16 + lr) * 8];
      o0 = __builtin_amdgcn_mfma_f32_16x16x32_bf16(pa, b0, o0, 0, 0, 0);
      o1 = __builtin_amdgcn_mfma_f32_16x16x32_bf16(pa, b1, o1, 0, 0, 0);
    }
    #pragma unroll
    for (int r = 0; r < 4; r++) {
      int n = row0 + g * 128 + wid * 16 + quad * 4 + r;
      size_t base = ((size_t)(b * 4096) + n) * 256 + h * 32;
      attn_out[base + lr] = f2bf(o0[r]);
      attn_out[base + 16 + lr] = f2bf(o1[r]);
    }
  }
}

extern "C" void kernel_launch(void* const* d_in, const int* in_sizes, int n_in,
                              void* d_out, int out_size, void* d_ws, size_t ws_size,
                              hipStream_t stream) {
  const float* x      = (const float*)d_in[0];
  const float* q_w    = (const float*)d_in[1];
  const float* q_b    = (const float*)d_in[2];
  const float* kv_w   = (const float*)d_in[3];
  const float* kv_b   = (const float*)d_in[4];
  const float* sr_w   = (const float*)d_in[5];
  const float* sr_b   = (const float*)d_in[6];
  const float* norm_g = (const float*)d_in[7];
  const float* norm_b = (const float*)d_in[8];
  const float* proj_w = (const float*)d_in[9];
  const float* proj_b = (const float*)d_in[10];
  float* out = (float*)d_out;

  char* ws = (char*)d_ws;
  unsigned short* q_wq    = (unsigned short*)(ws + 256);       // 128 KB
  unsigned short* kv_wq   = (unsigned short*)(ws + 131328);    // 256 KB
  unsigned short* proj_wq = (unsigned short*)(ws + 393472);    // 128 KB
  unsigned short* sr_wq   = (unsigned short*)(ws + 524544);    // 2 MB   -> 2621696
  unsigned short* xn      = (unsigned short*)(ws + 2621696);   // 1 MB   -> 3670272
  unsigned short* kqu     = (unsigned short*)(ws + 7864576);   // 1 MB (bf16 k)
  unsigned short* vqtu    = (unsigned short*)(ws + 8913152);   // 1 MB (bf16 v^T)
  float2*         rowstats= (float2*)(ws + 9961728);           // 2 MB   -> 12058880
  float*          convp   = (float*)(ws + 12058880);           // 8 MB (4 partials)
  unsigned short* attn_o  = (unsigned short*)(ws + 12058880);  // over convp (dead after k_ln); 16 MB
  float2*         pstat   = (float2*)(ws + 28836096);          // 8 KB
  unsigned short* qq      = (unsigned short*)(ws + 45613312);  // 16 MB (bf16 q)
  unsigned short* xb      = (unsigned short*)(ws + 62390528);  // 16 MB (x as bf16) -> 79167744
  float*          wredW   = (float*)(ws + 79167744);           // 1 KB (absmax partials)
  float*          wredG   = (float*)(ws + 79168768);           // 12 KB (gemm amax partials)

  k_absmax4<<<dim3(64, 4), 256, 0, stream>>>(q_w, kv_w, sr_w, proj_w, wredW);
  // weight quant + x->bf16 cast (reduces wredW in-prologue)
  k_quantw<<<4096, 256, 0, stream>>>(q_w, kv_w, proj_w, sr_w, x,
                                     q_wq, kv_wq, proj_wq, sr_wq, xb, wredW);
  // conv GEMM (im2col fused, split-K=4, XCD-swizzled): 2048x256x4096
  k_conv_sk<<<512, 256, 0, stream>>>(xb, sr_wq, convp);
  k_ln<<<2048, 256, 0, stream>>>(convp, sr_b, norm_g, norm_b, xn);
  // FUSED kv-GEMM (256 blocks) + q-GEMM (512 blocks); per-wave amax -> wredG
  k_gemm_qkv<<<768, 256, 0, stream>>>(xn, kv_wq, kv_b, xb, q_wq, q_b,
                                      kqu, vqtu, qq, wredG);
  // in-place fake-quant of q/k/v (reduces wredG in-prologue)
  k_quant_kvq<<<4608, 256, 0, stream>>>(qq, kqu, vqtu, wredG);
  // attn1: 512-thread blocks, full occupancy
  k_attn1<<<dim3(16, 64), 512, 0, stream>>>(qq, kqu, rowstats, pstat);
  // attn2: 512-thread blocks, pstat reduce in-prologue
  k_attn2<<<dim3(16, 64), 512, 0, stream>>>(qq, kqu, vqtu, pstat, rowstats, attn_o);
  // proj GEMM: 32768x256x256, 128-tile, XCD-swizzled
  k_gemm128<<<512, 256, 0, stream>>>(attn_o, proj_wq, proj_b, out);
}